// Round 1
// baseline (896.447 us; speedup 1.0000x reference)
//
#include <hip/hip_runtime.h>
#include <math.h>
#include <stdint.h>

#define B_  4
#define S_  2048
#define D_  1024
#define H_  16
#define DK_ 64
#define NR_ (B_ * S_)   // 8192 rows

typedef _Float16 half8  __attribute__((ext_vector_type(8)));
typedef _Float16 half4  __attribute__((ext_vector_type(4)));
typedef float    floatx4 __attribute__((ext_vector_type(4)));

// ---------------------------------------------------------------------------
// One-time fp32 -> split-f16 (hi/lo planes). Memory-bound; removes the
// 16x/64x-redundant per-tile conversion VALU from the GEMM K-loops.
// ---------------------------------------------------------------------------
__global__ __launch_bounds__(256)
void split_f32(const float* __restrict__ src, _Float16* __restrict__ hi,
               _Float16* __restrict__ lo, int n8) {
    const int i = blockIdx.x * 256 + threadIdx.x;
    if (i >= n8) return;
    const float4* s4 = (const float4*)src;
    float4 a = s4[2 * i];
    float4 b = s4[2 * i + 1];
    float f[8] = {a.x, a.y, a.z, a.w, b.x, b.y, b.z, b.w};
    union { half8 v; _Float16 h[8]; } H, L;
    #pragma unroll
    for (int j = 0; j < 8; ++j) {
        _Float16 h = (_Float16)f[j];
        H.h[j] = h;
        L.h[j] = (_Float16)(f[j] - (float)h);
    }
    *(half8*)(hi + (size_t)i * 8) = H.v;
    *(half8*)(lo + (size_t)i * 8) = L.v;
}

// ---------------------------------------------------------------------------
// GEMM: out = X @ W^T via split-f16 MFMA (fp32-accurate). Inputs are
// pre-split hi/lo f16 planes -> staging is pure uint4 copy (no VALU),
// with register prefetch of the next K-tile overlapping the MFMAs.
// Epilogue modes:
//   0: fp32 [N x M] row-major                        (Wo projection -> d_out)
//   1: hi/lo f16 planes, [B,H,S,DK]                  (Q,K projections)
//   2: f16 transposed head-split [B,H,DK,S]          (V projection)
// ---------------------------------------------------------------------------
#define GBN 128
#define GBM 64
#define GBK 32
#define LDH 40

__global__ __launch_bounds__(256)
void gemm_xwt_mfma(const _Float16* __restrict__ Xh, const _Float16* __restrict__ Xl,
                   const _Float16* __restrict__ Wh, const _Float16* __restrict__ Wl,
                   void* __restrict__ out0, void* __restrict__ out1, int mode) {
    __shared__ __align__(16) _Float16 Xhi[GBN][LDH];
    __shared__ __align__(16) _Float16 Xlo[GBN][LDH];
    __shared__ __align__(16) _Float16 Whi[GBM][LDH];
    __shared__ __align__(16) _Float16 Wlo[GBM][LDH];
    const int K = D_;

    const int tid  = threadIdx.x;
    const int wave = tid >> 6;
    const int lane = tid & 63;
    const int row16 = lane & 15;
    const int quad  = lane >> 4;
    const int n0 = blockIdx.x * GBN;
    const int m0 = blockIdx.y * GBM;

    // staging map: X 128 rows x 32 halves (2 threads/row), W 64 rows (4/row)
    const int xrow = tid >> 1;
    const int xc   = (tid & 1) << 4;
    const int wrow = tid >> 2;
    const int wc   = (tid & 3) << 3;

    floatx4 acc[2][4];
    const floatx4 zero4 = {0.f, 0.f, 0.f, 0.f};
    #pragma unroll
    for (int i = 0; i < 2; ++i)
        #pragma unroll
        for (int j = 0; j < 4; ++j) acc[i][j] = zero4;

    uint4 xh0, xh1, xl0, xl1, wh0, wl0;
    auto load_regs = [&](int k0) {
        const _Float16* ph = Xh + (size_t)(n0 + xrow) * K + k0 + xc;
        const _Float16* pl = Xl + (size_t)(n0 + xrow) * K + k0 + xc;
        xh0 = *(const uint4*)ph;
        xh1 = *(const uint4*)(ph + 8);
        xl0 = *(const uint4*)pl;
        xl1 = *(const uint4*)(pl + 8);
        const _Float16* pwh = Wh + (size_t)(m0 + wrow) * K + k0 + wc;
        const _Float16* pwl = Wl + (size_t)(m0 + wrow) * K + k0 + wc;
        wh0 = *(const uint4*)pwh;
        wl0 = *(const uint4*)pwl;
    };

    load_regs(0);
    for (int k0 = 0; k0 < K; k0 += GBK) {
        __syncthreads();
        *(uint4*)&Xhi[xrow][xc]     = xh0;
        *(uint4*)&Xhi[xrow][xc + 8] = xh1;
        *(uint4*)&Xlo[xrow][xc]     = xl0;
        *(uint4*)&Xlo[xrow][xc + 8] = xl1;
        *(uint4*)&Whi[wrow][wc]     = wh0;
        *(uint4*)&Wlo[wrow][wc]     = wl0;
        __syncthreads();
        if (k0 + GBK < K) load_regs(k0 + GBK);   // overlaps MFMAs below

        half8 a_hi[2], a_lo[2], b_hi[4], b_lo[4];
        #pragma unroll
        for (int ni = 0; ni < 2; ++ni) {
            const int r = wave * 32 + ni * 16 + row16;
            a_hi[ni] = *(const half8*)&Xhi[r][quad * 8];
            a_lo[ni] = *(const half8*)&Xlo[r][quad * 8];
        }
        #pragma unroll
        for (int mj = 0; mj < 4; ++mj) {
            const int r = mj * 16 + row16;
            b_hi[mj] = *(const half8*)&Whi[r][quad * 8];
            b_lo[mj] = *(const half8*)&Wlo[r][quad * 8];
        }

        #pragma unroll
        for (int ni = 0; ni < 2; ++ni)
            #pragma unroll
            for (int mj = 0; mj < 4; ++mj) {
                acc[ni][mj] = __builtin_amdgcn_mfma_f32_16x16x32_f16(
                    a_hi[ni], b_hi[mj], acc[ni][mj], 0, 0, 0);
                acc[ni][mj] = __builtin_amdgcn_mfma_f32_16x16x32_f16(
                    a_hi[ni], b_lo[mj], acc[ni][mj], 0, 0, 0);
                acc[ni][mj] = __builtin_amdgcn_mfma_f32_16x16x32_f16(
                    a_lo[ni], b_hi[mj], acc[ni][mj], 0, 0, 0);
            }
    }

    #pragma unroll
    for (int ni = 0; ni < 2; ++ni)
        #pragma unroll
        for (int mj = 0; mj < 4; ++mj) {
            if (mode == 2) {
                const int s  = n0 + wave * 32 + ni * 16 + quad * 4;
                const int b  = s >> 11;
                const int sr = s & (S_ - 1);
                const int m  = m0 + mj * 16 + row16;
                const int h  = m >> 6;
                const int dk = m & 63;
                half4 h4;
                #pragma unroll
                for (int r = 0; r < 4; ++r) h4[r] = (_Float16)acc[ni][mj][r];
                *(half4*)((_Float16*)out0 +
                          (((size_t)b * H_ + h) * DK_ + dk) * S_ + sr) = h4;
            } else {
                #pragma unroll
                for (int rg = 0; rg < 4; ++rg) {
                    const int n = n0 + wave * 32 + ni * 16 + quad * 4 + rg;
                    const int m = m0 + mj * 16 + row16;
                    const float v = acc[ni][mj][rg];
                    if (mode == 0) {
                        ((float*)out0)[(size_t)n * D_ + m] = v;
                    } else {
                        const int b  = n >> 11;
                        const int s  = n & (S_ - 1);
                        const int h  = m >> 6;
                        const int dk = m & 63;
                        _Float16 hi16 = (_Float16)v;
                        _Float16 lo16 = (_Float16)(v - (float)hi16);
                        const size_t idx = (((size_t)b * H_ + h) * S_ + s) * DK_ + dk;
                        ((_Float16*)out0)[idx] = hi16;
                        ((_Float16*)out1)[idx] = lo16;
                    }
                }
            }
        }
}

// ---------------------------------------------------------------------------
// MFMA flash attention v3: transposed-score formulation.
//   S^T = K·Q^T  (swap MFMA operands; C-layout col = q-row = lane&15)
//   -> softmax row reduction = in-lane over 16 k-values + 2 shuffles/tile
//   O^T = V^T·P^T (A = V^T rows from f16 [B,H,DK,S]; B = P rows via LDS)
// Inputs are pre-split f16 planes -> K/V staging is pure uint4 copy (no
// unpack/convert VALU). K/V LDS: XOR-swizzled 16B chunks (chunk ^ (row&7)).
// Diagonal-tile-only masking; t>wave tiles on diagonal skipped entirely.
// Register prefetch of tile kt+1 overlaps compute.
// Output written directly as split hi/lo f16 planes for the Wo GEMM.
// ---------------------------------------------------------------------------
__global__ __launch_bounds__(256)
void attn_mfma(const _Float16* __restrict__ Qhi_g, const _Float16* __restrict__ Qlo_g,
               const _Float16* __restrict__ Khi_g, const _Float16* __restrict__ Klo_g,
               const _Float16* __restrict__ Vth,
               _Float16* __restrict__ Ahi, _Float16* __restrict__ Alo) {
    __shared__ __align__(16) _Float16 KhiC[64][64];
    __shared__ __align__(16) _Float16 KloC[64][64];
    __shared__ __align__(16) _Float16 VC[64][64];
    __shared__ __align__(16) _Float16 PCT[4][16][72];   // [wave][q][k]

    const int bh = blockIdx.y;
    const int qt = (int)(gridDim.x - 1) - (int)blockIdx.x;  // heavy tiles first
    const int q0 = qt * 64;
    const int tid  = threadIdx.x;
    const int wave = tid >> 6;
    const int lane = tid & 63;
    const int c    = lane & 15;
    const int quad = lane >> 4;

    const _Float16* Kbh = Khi_g + (size_t)bh * S_ * DK_;
    const _Float16* Kbl = Klo_g + (size_t)bh * S_ * DK_;
    const _Float16* Vb  = Vth   + (size_t)bh * DK_ * S_;

    // Q fragment (B-operand): lane holds q-row (q0+16w+c), k = ks*32+quad*8+j
    half8 qhi[2], qlo[2];
    {
        const _Float16* Qrh = Qhi_g + ((size_t)bh * S_ + q0 + wave * 16 + c) * DK_;
        const _Float16* Qrl = Qlo_g + ((size_t)bh * S_ + q0 + wave * 16 + c) * DK_;
        #pragma unroll
        for (int ks = 0; ks < 2; ++ks) {
            qhi[ks] = *(const half8*)(Qrh + ks * 32 + quad * 8);
            qlo[ks] = *(const half8*)(Qrl + ks * 32 + quad * 8);
        }
    }

    floatx4 acc_o[4];   // O^T: acc_o[dt][r] = O[q=lane-col][dk=dt*16+quad*4+r]
    const floatx4 zero4 = {0.f, 0.f, 0.f, 0.f};
    #pragma unroll
    for (int dt = 0; dt < 4; ++dt) acc_o[dt] = zero4;
    float mrun = -INFINITY, lrun = 0.f;

    // staging: thread -> (row srow, 16-elem segment); chunk = 8 halves = 16 B
    const int srow = tid >> 2;
    const int soff = (tid & 3) * 16;
    const int ch0  = (tid & 3) * 2;

    uint4 kh[2], kl[2], vv[2];
    auto load_tile = [&](int kt) {
        const uint4* ph = (const uint4*)(Kbh + (size_t)(kt * 64 + srow) * DK_ + soff);
        kh[0] = ph[0]; kh[1] = ph[1];
        const uint4* pl = (const uint4*)(Kbl + (size_t)(kt * 64 + srow) * DK_ + soff);
        kl[0] = pl[0]; kl[1] = pl[1];
        const uint4* pv = (const uint4*)(Vb + (size_t)srow * S_ + kt * 64 + soff);
        vv[0] = pv[0]; vv[1] = pv[1];
    };
    auto write_tile = [&]() {
        #pragma unroll
        for (int hf = 0; hf < 2; ++hf) {
            const int swz = ((ch0 + hf) ^ (srow & 7)) * 8;
            *(uint4*)&KhiC[srow][swz] = kh[hf];
            *(uint4*)&KloC[srow][swz] = kl[hf];
            *(uint4*)&VC[srow][swz]   = vv[hf];
        }
    };

    const int qmy = q0 + wave * 16 + c;   // this lane's q-row
    const floatx4 neg4 = {-INFINITY, -INFINITY, -INFINITY, -INFINITY};

    load_tile(0);
    write_tile();

    for (int kt = 0; kt <= qt; ++kt) {
        const int k0 = kt * 64;
        const bool diag = (kt == qt);
        __syncthreads();                     // tile kt visible in LDS
        if (kt < qt) load_tile(kt + 1);      // prefetch overlaps compute

        // S^T tiles: sc[t][r] = S[q=qmy][k = k0 + t*16 + quad*4 + r] (unscaled)
        floatx4 sc[4];
        #pragma unroll
        for (int t = 0; t < 4; ++t) {
            if (diag && t > wave) { sc[t] = neg4; continue; }
            floatx4 s4 = zero4;
            const int krow = t * 16 + c;
            #pragma unroll
            for (int ks = 0; ks < 2; ++ks) {
                const int swz = ((ks * 4 + quad) ^ (krow & 7)) * 8;
                half8 kb = *(const half8*)&KhiC[krow][swz];
                half8 klo8 = *(const half8*)&KloC[krow][swz];
                s4 = __builtin_amdgcn_mfma_f32_16x16x32_f16(kb, qhi[ks], s4, 0, 0, 0);
                s4 = __builtin_amdgcn_mfma_f32_16x16x32_f16(klo8, qhi[ks], s4, 0, 0, 0);
                s4 = __builtin_amdgcn_mfma_f32_16x16x32_f16(kb, qlo[ks], s4, 0, 0, 0);
            }
            #pragma unroll
            for (int r = 0; r < 4; ++r) s4[r] *= 0.125f;
            if (diag && t == wave) {
                #pragma unroll
                for (int r = 0; r < 4; ++r) {
                    const int k = k0 + t * 16 + quad * 4 + r;
                    if (k > qmy) s4[r] = -INFINITY;
                }
            }
            sc[t] = s4;
        }

        // online softmax: in-lane max over 16, 2 cross-quad shuffles
        float mx = -INFINITY;
        #pragma unroll
        for (int t = 0; t < 4; ++t)
            #pragma unroll
            for (int r = 0; r < 4; ++r) mx = fmaxf(mx, sc[t][r]);
        mx = fmaxf(mx, __shfl_xor(mx, 16));
        mx = fmaxf(mx, __shfl_xor(mx, 32));
        const float mnew  = fmaxf(mrun, mx);
        const float alpha = __expf(mrun - mnew);
        float ls = 0.f;
        #pragma unroll
        for (int t = 0; t < 4; ++t) {
            half4 p4;
            #pragma unroll
            for (int r = 0; r < 4; ++r) {
                const float p = __expf(sc[t][r] - mnew);
                ls += p;
                p4[r] = (_Float16)p;
            }
            // P^T store: PCT[wave][q=c][k-local = t*16+quad*4 .. +3]
            *(half4*)&PCT[wave][c][t * 16 + quad * 4] = p4;
        }
        lrun = alpha * lrun + ls;
        mrun = mnew;
        #pragma unroll
        for (int dt = 0; dt < 4; ++dt)
            #pragma unroll
            for (int r = 0; r < 4; ++r) acc_o[dt][r] *= alpha;

        // O^T += V^T P^T  (A-frag = V^T rows, B-frag = P rows; same-wave RAW)
        #pragma unroll
        for (int kc = 0; kc < 2; ++kc) {
            if (diag && kc == 1 && wave < 2) continue;   // P chunk all-zero
            half8 pb = *(const half8*)&PCT[wave][c][kc * 32 + quad * 8];
            #pragma unroll
            for (int dt = 0; dt < 4; ++dt) {
                const int vrow = dt * 16 + c;
                const int swz = ((kc * 4 + quad) ^ (vrow & 7)) * 8;
                half8 va = *(const half8*)&VC[vrow][swz];
                acc_o[dt] = __builtin_amdgcn_mfma_f32_16x16x32_f16(va, pb, acc_o[dt], 0, 0, 0);
            }
        }

        __syncthreads();                     // all reads of tile kt done
        if (kt < qt) write_tile();
    }

    // final l across quads, normalize, write split hi/lo A planes [B,S,D]
    float l = lrun;
    l += __shfl_xor(l, 16);
    l += __shfl_xor(l, 32);
    const float inv = 1.f / l;
    const int b = bh >> 4, h = bh & 15;
    _Float16* dh = Ahi + ((size_t)b * S_ + qmy) * D_ + h * DK_;
    _Float16* dl = Alo + ((size_t)b * S_ + qmy) * D_ + h * DK_;
    #pragma unroll
    for (int dt = 0; dt < 4; ++dt) {
        half4 hh, ll;
        #pragma unroll
        for (int r = 0; r < 4; ++r) {
            const float o = acc_o[dt][r] * inv;
            hh[r] = (_Float16)o;
            ll[r] = (_Float16)(o - (float)hh[r]);
        }
        *(half4*)(dh + dt * 16 + quad * 4) = hh;
        *(half4*)(dl + dt * 16 + quad * 4) = ll;
    }
}

// ---------------------------------------------------------------------------
extern "C" void kernel_launch(void* const* d_in, const int* in_sizes, int n_in,
                              void* d_out, int out_size, void* d_ws, size_t ws_size,
                              hipStream_t stream) {
    const float* q  = (const float*)d_in[0];
    const float* k  = (const float*)d_in[1];
    const float* v  = (const float*)d_in[2];
    const float* Wq = (const float*)d_in[3];
    const float* Wk = (const float*)d_in[4];
    const float* Wv = (const float*)d_in[5];
    const float* Wo = (const float*)d_in[6];
    float* out = (float*)d_out;

    const size_t SZ  = (size_t)B_ * S_ * D_;   // 8,388,608 elements
    const size_t WSZ = (size_t)D_ * D_;        // 1,048,576 elements

    // workspace layout (halves): 7*SZ + 2*WSZ = 116 MB
    _Float16* ws  = (_Float16*)d_ws;
    _Float16* xhi = ws;              // [NR, D]  (reused as Ahi after V proj)
    _Float16* xlo = xhi + SZ;        // [NR, D]  (reused as Alo)
    _Float16* whi = xlo + SZ;        // [D, D]   (shared across the 4 weights)
    _Float16* wlo = whi + WSZ;
    _Float16* Qhi = wlo + WSZ;       // [B,H,S,DK]
    _Float16* Qlo = Qhi + SZ;
    _Float16* Khi = Qlo + SZ;        // [B,H,S,DK]
    _Float16* Klo = Khi + SZ;
    _Float16* Vth = Klo + SZ;        // [B,H,DK,S] f16
    _Float16* Ahi = xhi;
    _Float16* Alo = xlo;

    const int nx8 = (int)(SZ / 8);   // 1,048,576 -> 4096 blocks
    const int nw8 = (int)(WSZ / 8);  //   131,072 ->  512 blocks
    dim3 gb(NR_ / GBN, D_ / GBM);    // 64 x 16
    dim3 ga(S_ / 64, B_ * H_);       // 32 x 64

    split_f32<<<nw8 / 256, 256, 0, stream>>>(Wq, whi, wlo, nw8);
    split_f32<<<nx8 / 256, 256, 0, stream>>>(q, xhi, xlo, nx8);
    gemm_xwt_mfma<<<gb, 256, 0, stream>>>(xhi, xlo, whi, wlo, Qhi, Qlo, 1);

    split_f32<<<nw8 / 256, 256, 0, stream>>>(Wk, whi, wlo, nw8);
    split_f32<<<nx8 / 256, 256, 0, stream>>>(k, xhi, xlo, nx8);
    gemm_xwt_mfma<<<gb, 256, 0, stream>>>(xhi, xlo, whi, wlo, Khi, Klo, 1);

    split_f32<<<nw8 / 256, 256, 0, stream>>>(Wv, whi, wlo, nw8);
    split_f32<<<nx8 / 256, 256, 0, stream>>>(v, xhi, xlo, nx8);
    gemm_xwt_mfma<<<gb, 256, 0, stream>>>(xhi, xlo, whi, wlo, Vth, nullptr, 2);

    attn_mfma<<<ga, 256, 0, stream>>>(Qhi, Qlo, Khi, Klo, Vth, Ahi, Alo);

    split_f32<<<nw8 / 256, 256, 0, stream>>>(Wo, whi, wlo, nw8);
    gemm_xwt_mfma<<<gb, 256, 0, stream>>>(Ahi, Alo, whi, wlo, out, nullptr, 0);
}

// Round 2
// 870.774 us; speedup vs baseline: 1.0295x; 1.0295x over previous
//
#include <hip/hip_runtime.h>
#include <math.h>
#include <stdint.h>

#define B_  4
#define S_  2048
#define D_  1024
#define H_  16
#define DK_ 64
#define NR_ (B_ * S_)   // 8192 rows

typedef _Float16 half8  __attribute__((ext_vector_type(8)));
typedef _Float16 half4  __attribute__((ext_vector_type(4)));
typedef float    floatx4 __attribute__((ext_vector_type(4)));

// ---------------------------------------------------------------------------
// One-time fp32 -> split-f16 (hi/lo planes). Memory-bound; removes the
// 16x/64x-redundant per-tile conversion VALU from the GEMM K-loops.
// ---------------------------------------------------------------------------
__global__ __launch_bounds__(256)
void split_f32(const float* __restrict__ src, _Float16* __restrict__ hi,
               _Float16* __restrict__ lo, int n8) {
    const int i = blockIdx.x * 256 + threadIdx.x;
    if (i >= n8) return;
    const float4* s4 = (const float4*)src;
    float4 a = s4[2 * i];
    float4 b = s4[2 * i + 1];
    float f[8] = {a.x, a.y, a.z, a.w, b.x, b.y, b.z, b.w};
    union { half8 v; _Float16 h[8]; } H, L;
    #pragma unroll
    for (int j = 0; j < 8; ++j) {
        _Float16 h = (_Float16)f[j];
        H.h[j] = h;
        L.h[j] = (_Float16)(f[j] - (float)h);
    }
    *(half8*)(hi + (size_t)i * 8) = H.v;
    *(half8*)(lo + (size_t)i * 8) = L.v;
}

// ---------------------------------------------------------------------------
// GEMM: out = X @ W^T via split-f16 MFMA (fp32-accurate). Inputs are
// pre-split hi/lo f16 planes -> staging is pure uint4 copy (no VALU),
// with register prefetch of the next K-tile overlapping the MFMAs.
// __launch_bounds__(256,3): VGPR cap 170 (needs ~120) -> no scratch spill,
// occupancy floor 3 blocks/CU.
// Epilogue modes:
//   0: fp32 [N x M] row-major                        (Wo projection -> d_out)
//   1: hi/lo f16 planes, [B,H,S,DK]                  (Q,K projections)
//   2: f16 transposed head-split [B,H,DK,S]          (V projection)
// ---------------------------------------------------------------------------
#define GBN 128
#define GBM 64
#define GBK 32
#define LDH 40

__global__ __launch_bounds__(256, 3)
void gemm_xwt_mfma(const _Float16* __restrict__ Xh, const _Float16* __restrict__ Xl,
                   const _Float16* __restrict__ Wh, const _Float16* __restrict__ Wl,
                   void* __restrict__ out0, void* __restrict__ out1, int mode) {
    __shared__ __align__(16) _Float16 Xhi[GBN][LDH];
    __shared__ __align__(16) _Float16 Xlo[GBN][LDH];
    __shared__ __align__(16) _Float16 Whi[GBM][LDH];
    __shared__ __align__(16) _Float16 Wlo[GBM][LDH];
    const int K = D_;

    const int tid  = threadIdx.x;
    const int wave = tid >> 6;
    const int lane = tid & 63;
    const int row16 = lane & 15;
    const int quad  = lane >> 4;
    const int n0 = blockIdx.x * GBN;
    const int m0 = blockIdx.y * GBM;

    // staging map: X 128 rows x 32 halves (2 threads/row), W 64 rows (4/row)
    const int xrow = tid >> 1;
    const int xc   = (tid & 1) << 4;
    const int wrow = tid >> 2;
    const int wc   = (tid & 3) << 3;

    floatx4 acc[2][4];
    const floatx4 zero4 = {0.f, 0.f, 0.f, 0.f};
    #pragma unroll
    for (int i = 0; i < 2; ++i)
        #pragma unroll
        for (int j = 0; j < 4; ++j) acc[i][j] = zero4;

    uint4 xh0, xh1, xl0, xl1, wh0, wl0;
    auto load_regs = [&](int k0) {
        const _Float16* ph = Xh + (size_t)(n0 + xrow) * K + k0 + xc;
        const _Float16* pl = Xl + (size_t)(n0 + xrow) * K + k0 + xc;
        xh0 = *(const uint4*)ph;
        xh1 = *(const uint4*)(ph + 8);
        xl0 = *(const uint4*)pl;
        xl1 = *(const uint4*)(pl + 8);
        const _Float16* pwh = Wh + (size_t)(m0 + wrow) * K + k0 + wc;
        const _Float16* pwl = Wl + (size_t)(m0 + wrow) * K + k0 + wc;
        wh0 = *(const uint4*)pwh;
        wl0 = *(const uint4*)pwl;
    };

    load_regs(0);
    for (int k0 = 0; k0 < K; k0 += GBK) {
        __syncthreads();
        *(uint4*)&Xhi[xrow][xc]     = xh0;
        *(uint4*)&Xhi[xrow][xc + 8] = xh1;
        *(uint4*)&Xlo[xrow][xc]     = xl0;
        *(uint4*)&Xlo[xrow][xc + 8] = xl1;
        *(uint4*)&Whi[wrow][wc]     = wh0;
        *(uint4*)&Wlo[wrow][wc]     = wl0;
        __syncthreads();
        if (k0 + GBK < K) load_regs(k0 + GBK);   // overlaps MFMAs below

        half8 a_hi[2], a_lo[2], b_hi[4], b_lo[4];
        #pragma unroll
        for (int ni = 0; ni < 2; ++ni) {
            const int r = wave * 32 + ni * 16 + row16;
            a_hi[ni] = *(const half8*)&Xhi[r][quad * 8];
            a_lo[ni] = *(const half8*)&Xlo[r][quad * 8];
        }
        #pragma unroll
        for (int mj = 0; mj < 4; ++mj) {
            const int r = mj * 16 + row16;
            b_hi[mj] = *(const half8*)&Whi[r][quad * 8];
            b_lo[mj] = *(const half8*)&Wlo[r][quad * 8];
        }

        #pragma unroll
        for (int ni = 0; ni < 2; ++ni)
            #pragma unroll
            for (int mj = 0; mj < 4; ++mj) {
                acc[ni][mj] = __builtin_amdgcn_mfma_f32_16x16x32_f16(
                    a_hi[ni], b_hi[mj], acc[ni][mj], 0, 0, 0);
                acc[ni][mj] = __builtin_amdgcn_mfma_f32_16x16x32_f16(
                    a_hi[ni], b_lo[mj], acc[ni][mj], 0, 0, 0);
                acc[ni][mj] = __builtin_amdgcn_mfma_f32_16x16x32_f16(
                    a_lo[ni], b_hi[mj], acc[ni][mj], 0, 0, 0);
            }
    }

    #pragma unroll
    for (int ni = 0; ni < 2; ++ni)
        #pragma unroll
        for (int mj = 0; mj < 4; ++mj) {
            if (mode == 2) {
                const int s  = n0 + wave * 32 + ni * 16 + quad * 4;
                const int b  = s >> 11;
                const int sr = s & (S_ - 1);
                const int m  = m0 + mj * 16 + row16;
                const int h  = m >> 6;
                const int dk = m & 63;
                half4 h4;
                #pragma unroll
                for (int r = 0; r < 4; ++r) h4[r] = (_Float16)acc[ni][mj][r];
                *(half4*)((_Float16*)out0 +
                          (((size_t)b * H_ + h) * DK_ + dk) * S_ + sr) = h4;
            } else {
                #pragma unroll
                for (int rg = 0; rg < 4; ++rg) {
                    const int n = n0 + wave * 32 + ni * 16 + quad * 4 + rg;
                    const int m = m0 + mj * 16 + row16;
                    const float v = acc[ni][mj][rg];
                    if (mode == 0) {
                        ((float*)out0)[(size_t)n * D_ + m] = v;
                    } else {
                        const int b  = n >> 11;
                        const int s  = n & (S_ - 1);
                        const int h  = m >> 6;
                        const int dk = m & 63;
                        _Float16 hi16 = (_Float16)v;
                        _Float16 lo16 = (_Float16)(v - (float)hi16);
                        const size_t idx = (((size_t)b * H_ + h) * S_ + s) * DK_ + dk;
                        ((_Float16*)out0)[idx] = hi16;
                        ((_Float16*)out1)[idx] = lo16;
                    }
                }
            }
        }
}

// ---------------------------------------------------------------------------
// MFMA flash attention v3: transposed-score formulation.
//   S^T = K·Q^T  (swap MFMA operands; C-layout col = q-row = lane&15)
//   -> softmax row reduction = in-lane over 16 k-values + 2 shuffles/tile
//   O^T = V^T·P^T (A = V^T rows from f16 [B,H,DK,S]; B = P rows via LDS)
// Inputs are pre-split f16 planes -> K/V staging is pure uint4 copy (no
// unpack/convert VALU). K/V LDS: XOR-swizzled 16B chunks (chunk ^ (row&7)).
// Diagonal-tile-only masking; t>wave tiles on diagonal skipped entirely.
// Register prefetch of tile kt+1 overlaps compute.
// Output written directly as split hi/lo f16 planes for the Wo GEMM.
// __launch_bounds__(256,4): VGPR cap 128 (needs ~100) -> no scratch spill
// (round-1 regression: compiler chose 64 VGPR and spilled ~400 MB to
// scratch -> WRITE_SIZE 440 MB, dur 448 us). 4 blocks/CU matches the
// 33 KB LDS occupancy limit exactly.
// ---------------------------------------------------------------------------
__global__ __launch_bounds__(256, 4)
void attn_mfma(const _Float16* __restrict__ Qhi_g, const _Float16* __restrict__ Qlo_g,
               const _Float16* __restrict__ Khi_g, const _Float16* __restrict__ Klo_g,
               const _Float16* __restrict__ Vth,
               _Float16* __restrict__ Ahi, _Float16* __restrict__ Alo) {
    __shared__ __align__(16) _Float16 KhiC[64][64];
    __shared__ __align__(16) _Float16 KloC[64][64];
    __shared__ __align__(16) _Float16 VC[64][64];
    __shared__ __align__(16) _Float16 PCT[4][16][72];   // [wave][q][k]

    const int bh = blockIdx.y;
    const int qt = (int)(gridDim.x - 1) - (int)blockIdx.x;  // heavy tiles first
    const int q0 = qt * 64;
    const int tid  = threadIdx.x;
    const int wave = tid >> 6;
    const int lane = tid & 63;
    const int c    = lane & 15;
    const int quad = lane >> 4;

    const _Float16* Kbh = Khi_g + (size_t)bh * S_ * DK_;
    const _Float16* Kbl = Klo_g + (size_t)bh * S_ * DK_;
    const _Float16* Vb  = Vth   + (size_t)bh * DK_ * S_;

    // Q fragment (B-operand): lane holds q-row (q0+16w+c), k = ks*32+quad*8+j
    half8 qhi[2], qlo[2];
    {
        const _Float16* Qrh = Qhi_g + ((size_t)bh * S_ + q0 + wave * 16 + c) * DK_;
        const _Float16* Qrl = Qlo_g + ((size_t)bh * S_ + q0 + wave * 16 + c) * DK_;
        #pragma unroll
        for (int ks = 0; ks < 2; ++ks) {
            qhi[ks] = *(const half8*)(Qrh + ks * 32 + quad * 8);
            qlo[ks] = *(const half8*)(Qrl + ks * 32 + quad * 8);
        }
    }

    floatx4 acc_o[4];   // O^T: acc_o[dt][r] = O[q=lane-col][dk=dt*16+quad*4+r]
    const floatx4 zero4 = {0.f, 0.f, 0.f, 0.f};
    #pragma unroll
    for (int dt = 0; dt < 4; ++dt) acc_o[dt] = zero4;
    float mrun = -INFINITY, lrun = 0.f;

    // staging: thread -> (row srow, 16-elem segment); chunk = 8 halves = 16 B
    const int srow = tid >> 2;
    const int soff = (tid & 3) * 16;
    const int ch0  = (tid & 3) * 2;

    uint4 kh[2], kl[2], vv[2];
    auto load_tile = [&](int kt) {
        const uint4* ph = (const uint4*)(Kbh + (size_t)(kt * 64 + srow) * DK_ + soff);
        kh[0] = ph[0]; kh[1] = ph[1];
        const uint4* pl = (const uint4*)(Kbl + (size_t)(kt * 64 + srow) * DK_ + soff);
        kl[0] = pl[0]; kl[1] = pl[1];
        const uint4* pv = (const uint4*)(Vb + (size_t)srow * S_ + kt * 64 + soff);
        vv[0] = pv[0]; vv[1] = pv[1];
    };
    auto write_tile = [&]() {
        #pragma unroll
        for (int hf = 0; hf < 2; ++hf) {
            const int swz = ((ch0 + hf) ^ (srow & 7)) * 8;
            *(uint4*)&KhiC[srow][swz] = kh[hf];
            *(uint4*)&KloC[srow][swz] = kl[hf];
            *(uint4*)&VC[srow][swz]   = vv[hf];
        }
    };

    const int qmy = q0 + wave * 16 + c;   // this lane's q-row
    const floatx4 neg4 = {-INFINITY, -INFINITY, -INFINITY, -INFINITY};

    load_tile(0);
    write_tile();

    for (int kt = 0; kt <= qt; ++kt) {
        const int k0 = kt * 64;
        const bool diag = (kt == qt);
        __syncthreads();                     // tile kt visible in LDS
        if (kt < qt) load_tile(kt + 1);      // prefetch overlaps compute

        // S^T tiles: sc[t][r] = S[q=qmy][k = k0 + t*16 + quad*4 + r] (unscaled)
        floatx4 sc[4];
        #pragma unroll
        for (int t = 0; t < 4; ++t) {
            if (diag && t > wave) { sc[t] = neg4; continue; }
            floatx4 s4 = zero4;
            const int krow = t * 16 + c;
            #pragma unroll
            for (int ks = 0; ks < 2; ++ks) {
                const int swz = ((ks * 4 + quad) ^ (krow & 7)) * 8;
                half8 kb = *(const half8*)&KhiC[krow][swz];
                half8 klo8 = *(const half8*)&KloC[krow][swz];
                s4 = __builtin_amdgcn_mfma_f32_16x16x32_f16(kb, qhi[ks], s4, 0, 0, 0);
                s4 = __builtin_amdgcn_mfma_f32_16x16x32_f16(klo8, qhi[ks], s4, 0, 0, 0);
                s4 = __builtin_amdgcn_mfma_f32_16x16x32_f16(kb, qlo[ks], s4, 0, 0, 0);
            }
            #pragma unroll
            for (int r = 0; r < 4; ++r) s4[r] *= 0.125f;
            if (diag && t == wave) {
                #pragma unroll
                for (int r = 0; r < 4; ++r) {
                    const int k = k0 + t * 16 + quad * 4 + r;
                    if (k > qmy) s4[r] = -INFINITY;
                }
            }
            sc[t] = s4;
        }

        // online softmax: in-lane max over 16, 2 cross-quad shuffles
        float mx = -INFINITY;
        #pragma unroll
        for (int t = 0; t < 4; ++t)
            #pragma unroll
            for (int r = 0; r < 4; ++r) mx = fmaxf(mx, sc[t][r]);
        mx = fmaxf(mx, __shfl_xor(mx, 16));
        mx = fmaxf(mx, __shfl_xor(mx, 32));
        const float mnew  = fmaxf(mrun, mx);
        const float alpha = __expf(mrun - mnew);
        float ls = 0.f;
        #pragma unroll
        for (int t = 0; t < 4; ++t) {
            half4 p4;
            #pragma unroll
            for (int r = 0; r < 4; ++r) {
                const float p = __expf(sc[t][r] - mnew);
                ls += p;
                p4[r] = (_Float16)p;
            }
            // P^T store: PCT[wave][q=c][k-local = t*16+quad*4 .. +3]
            *(half4*)&PCT[wave][c][t * 16 + quad * 4] = p4;
        }
        lrun = alpha * lrun + ls;
        mrun = mnew;
        #pragma unroll
        for (int dt = 0; dt < 4; ++dt)
            #pragma unroll
            for (int r = 0; r < 4; ++r) acc_o[dt][r] *= alpha;

        // O^T += V^T P^T  (A-frag = V^T rows, B-frag = P rows; same-wave RAW)
        #pragma unroll
        for (int kc = 0; kc < 2; ++kc) {
            if (diag && kc == 1 && wave < 2) continue;   // P chunk all-zero
            half8 pb = *(const half8*)&PCT[wave][c][kc * 32 + quad * 8];
            #pragma unroll
            for (int dt = 0; dt < 4; ++dt) {
                const int vrow = dt * 16 + c;
                const int swz = ((kc * 4 + quad) ^ (vrow & 7)) * 8;
                half8 va = *(const half8*)&VC[vrow][swz];
                acc_o[dt] = __builtin_amdgcn_mfma_f32_16x16x32_f16(va, pb, acc_o[dt], 0, 0, 0);
            }
        }

        __syncthreads();                     // all reads of tile kt done
        if (kt < qt) write_tile();
    }

    // final l across quads, normalize, write split hi/lo A planes [B,S,D]
    float l = lrun;
    l += __shfl_xor(l, 16);
    l += __shfl_xor(l, 32);
    const float inv = 1.f / l;
    const int b = bh >> 4, h = bh & 15;
    _Float16* dh = Ahi + ((size_t)b * S_ + qmy) * D_ + h * DK_;
    _Float16* dl = Alo + ((size_t)b * S_ + qmy) * D_ + h * DK_;
    #pragma unroll
    for (int dt = 0; dt < 4; ++dt) {
        half4 hh, ll;
        #pragma unroll
        for (int r = 0; r < 4; ++r) {
            const float o = acc_o[dt][r] * inv;
            hh[r] = (_Float16)o;
            ll[r] = (_Float16)(o - (float)hh[r]);
        }
        *(half4*)(dh + dt * 16 + quad * 4) = hh;
        *(half4*)(dl + dt * 16 + quad * 4) = ll;
    }
}

// ---------------------------------------------------------------------------
extern "C" void kernel_launch(void* const* d_in, const int* in_sizes, int n_in,
                              void* d_out, int out_size, void* d_ws, size_t ws_size,
                              hipStream_t stream) {
    const float* q  = (const float*)d_in[0];
    const float* k  = (const float*)d_in[1];
    const float* v  = (const float*)d_in[2];
    const float* Wq = (const float*)d_in[3];
    const float* Wk = (const float*)d_in[4];
    const float* Wv = (const float*)d_in[5];
    const float* Wo = (const float*)d_in[6];
    float* out = (float*)d_out;

    const size_t SZ  = (size_t)B_ * S_ * D_;   // 8,388,608 elements
    const size_t WSZ = (size_t)D_ * D_;        // 1,048,576 elements

    // workspace layout (halves): 7*SZ + 2*WSZ = 116 MB
    _Float16* ws  = (_Float16*)d_ws;
    _Float16* xhi = ws;              // [NR, D]  (reused as Ahi after V proj)
    _Float16* xlo = xhi + SZ;        // [NR, D]  (reused as Alo)
    _Float16* whi = xlo + SZ;        // [D, D]   (shared across the 4 weights)
    _Float16* wlo = whi + WSZ;
    _Float16* Qhi = wlo + WSZ;       // [B,H,S,DK]
    _Float16* Qlo = Qhi + SZ;
    _Float16* Khi = Qlo + SZ;        // [B,H,S,DK]
    _Float16* Klo = Khi + SZ;
    _Float16* Vth = Klo + SZ;        // [B,H,DK,S] f16
    _Float16* Ahi = xhi;
    _Float16* Alo = xlo;

    const int nx8 = (int)(SZ / 8);   // 1,048,576 -> 4096 blocks
    const int nw8 = (int)(WSZ / 8);  //   131,072 ->  512 blocks
    dim3 gb(NR_ / GBN, D_ / GBM);    // 64 x 16
    dim3 ga(S_ / 64, B_ * H_);       // 32 x 64

    split_f32<<<nw8 / 256, 256, 0, stream>>>(Wq, whi, wlo, nw8);
    split_f32<<<nx8 / 256, 256, 0, stream>>>(q, xhi, xlo, nx8);
    gemm_xwt_mfma<<<gb, 256, 0, stream>>>(xhi, xlo, whi, wlo, Qhi, Qlo, 1);

    split_f32<<<nw8 / 256, 256, 0, stream>>>(Wk, whi, wlo, nw8);
    split_f32<<<nx8 / 256, 256, 0, stream>>>(k, xhi, xlo, nx8);
    gemm_xwt_mfma<<<gb, 256, 0, stream>>>(xhi, xlo, whi, wlo, Khi, Klo, 1);

    split_f32<<<nw8 / 256, 256, 0, stream>>>(Wv, whi, wlo, nw8);
    split_f32<<<nx8 / 256, 256, 0, stream>>>(v, xhi, xlo, nx8);
    gemm_xwt_mfma<<<gb, 256, 0, stream>>>(xhi, xlo, whi, wlo, Vth, nullptr, 2);

    attn_mfma<<<ga, 256, 0, stream>>>(Qhi, Qlo, Khi, Klo, Vth, Ahi, Alo);

    split_f32<<<nw8 / 256, 256, 0, stream>>>(Wo, whi, wlo, nw8);
    gemm_xwt_mfma<<<gb, 256, 0, stream>>>(Ahi, Alo, whi, wlo, out, nullptr, 0);
}

// Round 3
// 666.591 us; speedup vs baseline: 1.3448x; 1.3063x over previous
//
#include <hip/hip_runtime.h>
#include <math.h>
#include <stdint.h>

#define B_  4
#define S_  2048
#define D_  1024
#define H_  16
#define DK_ 64
#define NR_ (B_ * S_)   // 8192 rows

typedef _Float16 half8  __attribute__((ext_vector_type(8)));
typedef _Float16 half4  __attribute__((ext_vector_type(4)));
typedef float    floatx4 __attribute__((ext_vector_type(4)));

// ---------------------------------------------------------------------------
// One-time fp32 -> split-f16 (hi/lo planes) for GEMM inputs. Memory-bound.
// ---------------------------------------------------------------------------
__global__ __launch_bounds__(256)
void split_f32(const float* __restrict__ src, _Float16* __restrict__ hi,
               _Float16* __restrict__ lo, int n8) {
    const int i = blockIdx.x * 256 + threadIdx.x;
    if (i >= n8) return;
    const float4* s4 = (const float4*)src;
    float4 a = s4[2 * i];
    float4 b = s4[2 * i + 1];
    float f[8] = {a.x, a.y, a.z, a.w, b.x, b.y, b.z, b.w};
    union { half8 v; _Float16 h[8]; } H, L;
    #pragma unroll
    for (int j = 0; j < 8; ++j) {
        _Float16 h = (_Float16)f[j];
        H.h[j] = h;
        L.h[j] = (_Float16)(f[j] - (float)h);
    }
    *(half8*)(hi + (size_t)i * 8) = H.v;
    *(half8*)(lo + (size_t)i * 8) = L.v;
}

// ---------------------------------------------------------------------------
// GEMM: out = X @ W^T via split-f16 MFMA (fp32-accurate). Inputs are
// pre-split hi/lo f16 planes -> staging is pure uint4 copy (no VALU),
// with register prefetch of the next K-tile overlapping the MFMAs.
// (This K-loop structure measured ~92 us/GEMM in round 2 vs 124 us round 0.)
// Epilogue modes:
//   0: fp32 [N x M] row-major                        (Wo projection -> d_out)
//   1: packed u32 {lo16,hi16} f16 split, [B,H,S,DK]  (Q,K projections --
//      round-0 format: feeds the proven attn staging codegen)
//   2: f16 transposed head-split [B,H,DK,S]          (V projection)
// ---------------------------------------------------------------------------
#define GBN 128
#define GBM 64
#define GBK 32
#define LDH 40

__global__ __launch_bounds__(256, 3)
void gemm_xwt_mfma(const _Float16* __restrict__ Xh, const _Float16* __restrict__ Xl,
                   const _Float16* __restrict__ Wh, const _Float16* __restrict__ Wl,
                   void* __restrict__ out0, int mode) {
    __shared__ __align__(16) _Float16 Xhi[GBN][LDH];
    __shared__ __align__(16) _Float16 Xlo[GBN][LDH];
    __shared__ __align__(16) _Float16 Whi[GBM][LDH];
    __shared__ __align__(16) _Float16 Wlo[GBM][LDH];
    const int K = D_;

    const int tid  = threadIdx.x;
    const int wave = tid >> 6;
    const int lane = tid & 63;
    const int row16 = lane & 15;
    const int quad  = lane >> 4;
    const int n0 = blockIdx.x * GBN;
    const int m0 = blockIdx.y * GBM;

    // staging map: X 128 rows x 32 halves (2 threads/row), W 64 rows (4/row)
    const int xrow = tid >> 1;
    const int xc   = (tid & 1) << 4;
    const int wrow = tid >> 2;
    const int wc   = (tid & 3) << 3;

    floatx4 acc[2][4];
    const floatx4 zero4 = {0.f, 0.f, 0.f, 0.f};
    #pragma unroll
    for (int i = 0; i < 2; ++i)
        #pragma unroll
        for (int j = 0; j < 4; ++j) acc[i][j] = zero4;

    uint4 xh0, xh1, xl0, xl1, wh0, wl0;
    auto load_regs = [&](int k0) {
        const _Float16* ph = Xh + (size_t)(n0 + xrow) * K + k0 + xc;
        const _Float16* pl = Xl + (size_t)(n0 + xrow) * K + k0 + xc;
        xh0 = *(const uint4*)ph;
        xh1 = *(const uint4*)(ph + 8);
        xl0 = *(const uint4*)pl;
        xl1 = *(const uint4*)(pl + 8);
        const _Float16* pwh = Wh + (size_t)(m0 + wrow) * K + k0 + wc;
        const _Float16* pwl = Wl + (size_t)(m0 + wrow) * K + k0 + wc;
        wh0 = *(const uint4*)pwh;
        wl0 = *(const uint4*)pwl;
    };

    load_regs(0);
    for (int k0 = 0; k0 < K; k0 += GBK) {
        __syncthreads();
        *(uint4*)&Xhi[xrow][xc]     = xh0;
        *(uint4*)&Xhi[xrow][xc + 8] = xh1;
        *(uint4*)&Xlo[xrow][xc]     = xl0;
        *(uint4*)&Xlo[xrow][xc + 8] = xl1;
        *(uint4*)&Whi[wrow][wc]     = wh0;
        *(uint4*)&Wlo[wrow][wc]     = wl0;
        __syncthreads();
        if (k0 + GBK < K) load_regs(k0 + GBK);   // overlaps MFMAs below

        half8 a_hi[2], a_lo[2], b_hi[4], b_lo[4];
        #pragma unroll
        for (int ni = 0; ni < 2; ++ni) {
            const int r = wave * 32 + ni * 16 + row16;
            a_hi[ni] = *(const half8*)&Xhi[r][quad * 8];
            a_lo[ni] = *(const half8*)&Xlo[r][quad * 8];
        }
        #pragma unroll
        for (int mj = 0; mj < 4; ++mj) {
            const int r = mj * 16 + row16;
            b_hi[mj] = *(const half8*)&Whi[r][quad * 8];
            b_lo[mj] = *(const half8*)&Wlo[r][quad * 8];
        }

        #pragma unroll
        for (int ni = 0; ni < 2; ++ni)
            #pragma unroll
            for (int mj = 0; mj < 4; ++mj) {
                acc[ni][mj] = __builtin_amdgcn_mfma_f32_16x16x32_f16(
                    a_hi[ni], b_hi[mj], acc[ni][mj], 0, 0, 0);
                acc[ni][mj] = __builtin_amdgcn_mfma_f32_16x16x32_f16(
                    a_hi[ni], b_lo[mj], acc[ni][mj], 0, 0, 0);
                acc[ni][mj] = __builtin_amdgcn_mfma_f32_16x16x32_f16(
                    a_lo[ni], b_hi[mj], acc[ni][mj], 0, 0, 0);
            }
    }

    #pragma unroll
    for (int ni = 0; ni < 2; ++ni)
        #pragma unroll
        for (int mj = 0; mj < 4; ++mj) {
            if (mode == 2) {
                const int s  = n0 + wave * 32 + ni * 16 + quad * 4;
                const int b  = s >> 11;
                const int sr = s & (S_ - 1);
                const int m  = m0 + mj * 16 + row16;
                const int h  = m >> 6;
                const int dk = m & 63;
                half4 h4;
                #pragma unroll
                for (int r = 0; r < 4; ++r) h4[r] = (_Float16)acc[ni][mj][r];
                *(half4*)((_Float16*)out0 +
                          (((size_t)b * H_ + h) * DK_ + dk) * S_ + sr) = h4;
            } else {
                #pragma unroll
                for (int rg = 0; rg < 4; ++rg) {
                    const int n = n0 + wave * 32 + ni * 16 + quad * 4 + rg;
                    const int m = m0 + mj * 16 + row16;
                    const float v = acc[ni][mj][rg];
                    if (mode == 0) {
                        ((float*)out0)[(size_t)n * D_ + m] = v;
                    } else {
                        const int b  = n >> 11;
                        const int s  = n & (S_ - 1);
                        const int h  = m >> 6;
                        const int dk = m & 63;
                        union { _Float16 h16; uint16_t u; } hi, lo;
                        hi.h16 = (_Float16)v;
                        lo.h16 = (_Float16)(v - (float)hi.h16);
                        uint32_t u = ((uint32_t)lo.u << 16) | (uint32_t)hi.u;
                        ((uint32_t*)out0)[(((size_t)b * H_ + h) * S_ + s) * DK_ + dk] = u;
                    }
                }
            }
        }
}

// ---------------------------------------------------------------------------
// MFMA flash attention v3 -- round-0 structure restored verbatim (that
// codegen is proven: VGPR 84, zero scratch, 202 us; the round-1/2 direct
// plane-staging variant spilled ~400 MB scratch regardless of
// __launch_bounds__). Q/K arrive packed u32 {lo16,hi16}; unpack in staging
// (cheap bitops). Two pressure-reducing deltas vs round 0:
//   * V arrives f16 [B,H,DK,S] -> V staging is pure uint4 copy (fewer regs
//     than round 0's float4+cvt; identical value, cvt moved to GEMM).
//   * epilogue writes split hi/lo f16 A planes (feeds fast Wo GEMM path).
// ---------------------------------------------------------------------------
__global__ __launch_bounds__(256)
void attn_mfma(const uint32_t* __restrict__ Qhl, const uint32_t* __restrict__ Khl,
               const _Float16* __restrict__ Vth,
               _Float16* __restrict__ Ahi, _Float16* __restrict__ Alo) {
    __shared__ __align__(16) _Float16 KhiC[64][64];
    __shared__ __align__(16) _Float16 KloC[64][64];
    __shared__ __align__(16) _Float16 VC[64][64];
    __shared__ __align__(16) _Float16 PCT[4][16][72];   // [wave][q][k]

    const int bh = blockIdx.y;
    const int qt = (int)(gridDim.x - 1) - (int)blockIdx.x;  // heavy tiles first
    const int q0 = qt * 64;
    const int tid  = threadIdx.x;
    const int wave = tid >> 6;
    const int lane = tid & 63;
    const int c    = lane & 15;
    const int quad = lane >> 4;

    const uint32_t* Kb = Khl + (size_t)bh * S_ * DK_;
    const _Float16* Vb = Vth + (size_t)bh * DK_ * S_;

    // Q fragment (B-operand): lane holds q-row (q0+16w+c), k = ks*32+quad*8+j
    half8 qhi[2], qlo[2];
    {
        const uint32_t* Qrow = Qhl + ((size_t)bh * S_ + q0 + wave * 16 + c) * DK_;
        #pragma unroll
        for (int ks = 0; ks < 2; ++ks) {
            uint32_t u[8];
            *(uint4*)&u[0] = *(const uint4*)(Qrow + ks * 32 + quad * 8);
            *(uint4*)&u[4] = *(const uint4*)(Qrow + ks * 32 + quad * 8 + 4);
            union { half8 v; uint16_t s[8]; } hi, lo;
            #pragma unroll
            for (int j = 0; j < 8; ++j) {
                hi.s[j] = (uint16_t)(u[j] & 0xffffu);
                lo.s[j] = (uint16_t)(u[j] >> 16);
            }
            qhi[ks] = hi.v; qlo[ks] = lo.v;
        }
    }

    floatx4 acc_o[4];   // O^T: acc_o[dt][r] = O[q=lane-col][dk=dt*16+quad*4+r]
    const floatx4 zero4 = {0.f, 0.f, 0.f, 0.f};
    #pragma unroll
    for (int dt = 0; dt < 4; ++dt) acc_o[dt] = zero4;
    float mrun = -INFINITY, lrun = 0.f;

    // staging: thread -> (row srow, 16-elem segment); chunk = 8 halves = 16 B
    const int srow = tid >> 2;
    const int soff = (tid & 3) * 16;
    const int ch0  = (tid & 3) * 2;

    uint4 ku[4];
    uint4 vv[2];
    auto load_tile = [&](int kt) {
        const uint4* ksrc = (const uint4*)(Kb + (size_t)(kt * 64 + srow) * DK_ + soff);
        ku[0] = ksrc[0]; ku[1] = ksrc[1]; ku[2] = ksrc[2]; ku[3] = ksrc[3];
        const uint4* vsrc = (const uint4*)(Vb + (size_t)srow * S_ + kt * 64 + soff);
        vv[0] = vsrc[0]; vv[1] = vsrc[1];
    };
    auto write_tile = [&]() {
        #pragma unroll
        for (int hf = 0; hf < 2; ++hf) {
            const int swz = ((ch0 + hf) ^ (srow & 7)) * 8;
            uint32_t uu[8];
            *(uint4*)&uu[0] = ku[2 * hf];
            *(uint4*)&uu[4] = ku[2 * hf + 1];
            union { half8 v; uint16_t s[8]; } hi, lo;
            #pragma unroll
            for (int j = 0; j < 8; ++j) {
                hi.s[j] = (uint16_t)(uu[j] & 0xffffu);
                lo.s[j] = (uint16_t)(uu[j] >> 16);
            }
            *(half8*)&KhiC[srow][swz] = hi.v;
            *(half8*)&KloC[srow][swz] = lo.v;
            *(uint4*)&VC[srow][swz]   = vv[hf];
        }
    };

    const int qmy = q0 + wave * 16 + c;   // this lane's q-row
    const floatx4 neg4 = {-INFINITY, -INFINITY, -INFINITY, -INFINITY};

    load_tile(0);
    write_tile();

    for (int kt = 0; kt <= qt; ++kt) {
        const int k0 = kt * 64;
        const bool diag = (kt == qt);
        __syncthreads();                     // tile kt visible in LDS
        if (kt < qt) load_tile(kt + 1);      // prefetch overlaps compute

        // S^T tiles: sc[t][r] = S[q=qmy][k = k0 + t*16 + quad*4 + r] (unscaled)
        floatx4 sc[4];
        #pragma unroll
        for (int t = 0; t < 4; ++t) {
            if (diag && t > wave) { sc[t] = neg4; continue; }
            floatx4 s4 = zero4;
            const int krow = t * 16 + c;
            #pragma unroll
            for (int ks = 0; ks < 2; ++ks) {
                const int swz = ((ks * 4 + quad) ^ (krow & 7)) * 8;
                half8 kb = *(const half8*)&KhiC[krow][swz];
                half8 kl = *(const half8*)&KloC[krow][swz];
                s4 = __builtin_amdgcn_mfma_f32_16x16x32_f16(kb, qhi[ks], s4, 0, 0, 0);
                s4 = __builtin_amdgcn_mfma_f32_16x16x32_f16(kl, qhi[ks], s4, 0, 0, 0);
                s4 = __builtin_amdgcn_mfma_f32_16x16x32_f16(kb, qlo[ks], s4, 0, 0, 0);
            }
            #pragma unroll
            for (int r = 0; r < 4; ++r) s4[r] *= 0.125f;
            if (diag && t == wave) {
                #pragma unroll
                for (int r = 0; r < 4; ++r) {
                    const int k = k0 + t * 16 + quad * 4 + r;
                    if (k > qmy) s4[r] = -INFINITY;
                }
            }
            sc[t] = s4;
        }

        // online softmax: in-lane max over 16, 2 cross-quad shuffles
        float mx = -INFINITY;
        #pragma unroll
        for (int t = 0; t < 4; ++t)
            #pragma unroll
            for (int r = 0; r < 4; ++r) mx = fmaxf(mx, sc[t][r]);
        mx = fmaxf(mx, __shfl_xor(mx, 16));
        mx = fmaxf(mx, __shfl_xor(mx, 32));
        const float mnew  = fmaxf(mrun, mx);
        const float alpha = __expf(mrun - mnew);
        float ls = 0.f;
        #pragma unroll
        for (int t = 0; t < 4; ++t) {
            half4 p4;
            #pragma unroll
            for (int r = 0; r < 4; ++r) {
                const float p = __expf(sc[t][r] - mnew);
                ls += p;
                p4[r] = (_Float16)p;
            }
            // P^T store: PCT[wave][q=c][k-local = t*16+quad*4 .. +3]
            *(half4*)&PCT[wave][c][t * 16 + quad * 4] = p4;
        }
        lrun = alpha * lrun + ls;
        mrun = mnew;
        #pragma unroll
        for (int dt = 0; dt < 4; ++dt)
            #pragma unroll
            for (int r = 0; r < 4; ++r) acc_o[dt][r] *= alpha;

        // O^T += V^T P^T  (A-frag = V^T rows, B-frag = P rows; same-wave RAW)
        #pragma unroll
        for (int kc = 0; kc < 2; ++kc) {
            if (diag && kc == 1 && wave < 2) continue;   // P chunk all-zero
            half8 pb = *(const half8*)&PCT[wave][c][kc * 32 + quad * 8];
            #pragma unroll
            for (int dt = 0; dt < 4; ++dt) {
                const int vrow = dt * 16 + c;
                const int swz = ((kc * 4 + quad) ^ (vrow & 7)) * 8;
                half8 va = *(const half8*)&VC[vrow][swz];
                acc_o[dt] = __builtin_amdgcn_mfma_f32_16x16x32_f16(va, pb, acc_o[dt], 0, 0, 0);
            }
        }

        __syncthreads();                     // all reads of tile kt done
        if (kt < qt) write_tile();
    }

    // final l across quads, normalize, write split hi/lo A planes [B,S,D]
    float l = lrun;
    l += __shfl_xor(l, 16);
    l += __shfl_xor(l, 32);
    const float inv = 1.f / l;
    const int b = bh >> 4, h = bh & 15;
    _Float16* dh = Ahi + ((size_t)b * S_ + qmy) * D_ + h * DK_;
    _Float16* dl = Alo + ((size_t)b * S_ + qmy) * D_ + h * DK_;
    #pragma unroll
    for (int dt = 0; dt < 4; ++dt) {
        half4 hh, ll;
        #pragma unroll
        for (int r = 0; r < 4; ++r) {
            const float o = acc_o[dt][r] * inv;
            hh[r] = (_Float16)o;
            ll[r] = (_Float16)(o - (float)hh[r]);
        }
        *(half4*)(dh + dt * 16 + quad * 4) = hh;
        *(half4*)(dl + dt * 16 + quad * 4) = ll;
    }
}

// ---------------------------------------------------------------------------
extern "C" void kernel_launch(void* const* d_in, const int* in_sizes, int n_in,
                              void* d_out, int out_size, void* d_ws, size_t ws_size,
                              hipStream_t stream) {
    const float* q  = (const float*)d_in[0];
    const float* k  = (const float*)d_in[1];
    const float* v  = (const float*)d_in[2];
    const float* Wq = (const float*)d_in[3];
    const float* Wk = (const float*)d_in[4];
    const float* Wv = (const float*)d_in[5];
    const float* Wo = (const float*)d_in[6];
    float* out = (float*)d_out;

    const size_t SZ  = (size_t)B_ * S_ * D_;   // 8,388,608 elements
    const size_t WSZ = (size_t)D_ * D_;        // 1,048,576 elements

    // workspace layout (in halves): 7*SZ + 2*WSZ = ~122 MB
    _Float16* ws  = (_Float16*)d_ws;
    _Float16* xhi = ws;                        // [NR, D]  (reused as Ahi)
    _Float16* xlo = xhi + SZ;                  // [NR, D]  (reused as Alo)
    _Float16* whi = xlo + SZ;                  // [D, D]   (shared by 4 weights)
    _Float16* wlo = whi + WSZ;
    uint32_t* Qhl = (uint32_t*)(wlo + WSZ);    // packed u32 [B,H,S,DK] (2*SZ halves)
    uint32_t* Khl = (uint32_t*)(wlo + WSZ + 2 * SZ);  // packed u32 (2*SZ halves)
    _Float16* Vth = wlo + WSZ + 4 * SZ;        // f16 [B,H,DK,S] (SZ halves)
    _Float16* Ahi = xhi;
    _Float16* Alo = xlo;

    const int nx8 = (int)(SZ / 8);   // 1,048,576 -> 4096 blocks
    const int nw8 = (int)(WSZ / 8);  //   131,072 ->  512 blocks
    dim3 gb(NR_ / GBN, D_ / GBM);    // 64 x 16
    dim3 ga(S_ / 64, B_ * H_);       // 32 x 64

    split_f32<<<nw8 / 256, 256, 0, stream>>>(Wq, whi, wlo, nw8);
    split_f32<<<nx8 / 256, 256, 0, stream>>>(q, xhi, xlo, nx8);
    gemm_xwt_mfma<<<gb, 256, 0, stream>>>(xhi, xlo, whi, wlo, Qhl, 1);

    split_f32<<<nw8 / 256, 256, 0, stream>>>(Wk, whi, wlo, nw8);
    split_f32<<<nx8 / 256, 256, 0, stream>>>(k, xhi, xlo, nx8);
    gemm_xwt_mfma<<<gb, 256, 0, stream>>>(xhi, xlo, whi, wlo, Khl, 1);

    split_f32<<<nw8 / 256, 256, 0, stream>>>(Wv, whi, wlo, nw8);
    split_f32<<<nx8 / 256, 256, 0, stream>>>(v, xhi, xlo, nx8);
    gemm_xwt_mfma<<<gb, 256, 0, stream>>>(xhi, xlo, whi, wlo, Vth, 2);

    attn_mfma<<<ga, 256, 0, stream>>>(Qhl, Khl, Vth, Ahi, Alo);

    split_f32<<<nw8 / 256, 256, 0, stream>>>(Wo, whi, wlo, nw8);
    gemm_xwt_mfma<<<gb, 256, 0, stream>>>(Ahi, Alo, whi, wlo, out, 0);
}

// Round 4
// 623.049 us; speedup vs baseline: 1.4388x; 1.0699x over previous
//
#include <hip/hip_runtime.h>
#include <math.h>
#include <stdint.h>

#define B_  4
#define S_  2048
#define D_  1024
#define H_  16
#define DK_ 64
#define NR_ (B_ * S_)   // 8192 rows

typedef _Float16 half8  __attribute__((ext_vector_type(8)));
typedef _Float16 half4  __attribute__((ext_vector_type(4)));
typedef float    floatx4 __attribute__((ext_vector_type(4)));

// ---------------------------------------------------------------------------
// One-time fp32 -> split-f16 (hi/lo planes) for GEMM inputs. Memory-bound.
// ---------------------------------------------------------------------------
__global__ __launch_bounds__(256)
void split_f32(const float* __restrict__ src, _Float16* __restrict__ hi,
               _Float16* __restrict__ lo, int n8) {
    const int i = blockIdx.x * 256 + threadIdx.x;
    if (i >= n8) return;
    const float4* s4 = (const float4*)src;
    float4 a = s4[2 * i];
    float4 b = s4[2 * i + 1];
    float f[8] = {a.x, a.y, a.z, a.w, b.x, b.y, b.z, b.w};
    union { half8 v; _Float16 h[8]; } H, L;
    #pragma unroll
    for (int j = 0; j < 8; ++j) {
        _Float16 h = (_Float16)f[j];
        H.h[j] = h;
        L.h[j] = (_Float16)(f[j] - (float)h);
    }
    *(half8*)(hi + (size_t)i * 8) = H.v;
    *(half8*)(lo + (size_t)i * 8) = L.v;
}

// ---------------------------------------------------------------------------
// GEMM: out = X @ W^T via split-f16 MFMA (fp32-accurate). Inputs are
// pre-split hi/lo f16 planes -> staging is pure uint4 copy (no VALU),
// with register prefetch of the next K-tile overlapping the MFMAs.
// Round-4: tile 128x128 (was 128x64). Theory: round-3 GEMM was operand-
// refetch bound (768 MB L2/L3 traffic at ~8.3 TB/s); 128x128 cuts traffic
// to 512 MB and lets 64 consecutive x-blocks share one L2-resident W panel.
// b-fragments loaded inside the mj loop to cap VGPR (~145 < 170 cap).
// Epilogue modes:
//   0: fp32 [N x M] row-major                        (Wo projection -> d_out)
//   1: packed u32 {lo16,hi16} f16 split, [B,H,S,DK]  (Q,K projections)
//   2: f16 transposed head-split [B,H,DK,S]          (V projection)
// ---------------------------------------------------------------------------
#define GBN 128
#define GBM 128
#define GBK 32
#define LDH 40

__global__ __launch_bounds__(256, 3)
void gemm_xwt_mfma(const _Float16* __restrict__ Xh, const _Float16* __restrict__ Xl,
                   const _Float16* __restrict__ Wh, const _Float16* __restrict__ Wl,
                   void* __restrict__ out0, int mode) {
    __shared__ __align__(16) _Float16 Xhi[GBN][LDH];
    __shared__ __align__(16) _Float16 Xlo[GBN][LDH];
    __shared__ __align__(16) _Float16 Whi[GBM][LDH];
    __shared__ __align__(16) _Float16 Wlo[GBM][LDH];
    const int K = D_;

    const int tid  = threadIdx.x;
    const int wave = tid >> 6;
    const int lane = tid & 63;
    const int row16 = lane & 15;
    const int quad  = lane >> 4;
    const int n0 = blockIdx.x * GBN;
    const int m0 = blockIdx.y * GBM;

    // staging map: 128 rows x 32 halves, 2 threads/row (16 halves each)
    const int xrow = tid >> 1;
    const int xc   = (tid & 1) << 4;

    floatx4 acc[2][8];
    const floatx4 zero4 = {0.f, 0.f, 0.f, 0.f};
    #pragma unroll
    for (int i = 0; i < 2; ++i)
        #pragma unroll
        for (int j = 0; j < 8; ++j) acc[i][j] = zero4;

    uint4 xh0, xh1, xl0, xl1, wh0, wh1, wl0, wl1;
    auto load_regs = [&](int k0) {
        const _Float16* ph = Xh + (size_t)(n0 + xrow) * K + k0 + xc;
        const _Float16* pl = Xl + (size_t)(n0 + xrow) * K + k0 + xc;
        xh0 = *(const uint4*)ph;
        xh1 = *(const uint4*)(ph + 8);
        xl0 = *(const uint4*)pl;
        xl1 = *(const uint4*)(pl + 8);
        const _Float16* pwh = Wh + (size_t)(m0 + xrow) * K + k0 + xc;
        const _Float16* pwl = Wl + (size_t)(m0 + xrow) * K + k0 + xc;
        wh0 = *(const uint4*)pwh;
        wh1 = *(const uint4*)(pwh + 8);
        wl0 = *(const uint4*)pwl;
        wl1 = *(const uint4*)(pwl + 8);
    };

    load_regs(0);
    for (int k0 = 0; k0 < K; k0 += GBK) {
        __syncthreads();
        *(uint4*)&Xhi[xrow][xc]     = xh0;
        *(uint4*)&Xhi[xrow][xc + 8] = xh1;
        *(uint4*)&Xlo[xrow][xc]     = xl0;
        *(uint4*)&Xlo[xrow][xc + 8] = xl1;
        *(uint4*)&Whi[xrow][xc]     = wh0;
        *(uint4*)&Whi[xrow][xc + 8] = wh1;
        *(uint4*)&Wlo[xrow][xc]     = wl0;
        *(uint4*)&Wlo[xrow][xc + 8] = wl1;
        __syncthreads();
        if (k0 + GBK < K) load_regs(k0 + GBK);   // overlaps MFMAs below

        half8 a_hi[2], a_lo[2];
        #pragma unroll
        for (int ni = 0; ni < 2; ++ni) {
            const int r = wave * 32 + ni * 16 + row16;
            a_hi[ni] = *(const half8*)&Xhi[r][quad * 8];
            a_lo[ni] = *(const half8*)&Xlo[r][quad * 8];
        }
        #pragma unroll
        for (int mj = 0; mj < 8; ++mj) {
            const int r = mj * 16 + row16;
            half8 b_hi = *(const half8*)&Whi[r][quad * 8];
            half8 b_lo = *(const half8*)&Wlo[r][quad * 8];
            #pragma unroll
            for (int ni = 0; ni < 2; ++ni) {
                acc[ni][mj] = __builtin_amdgcn_mfma_f32_16x16x32_f16(
                    a_hi[ni], b_hi, acc[ni][mj], 0, 0, 0);
                acc[ni][mj] = __builtin_amdgcn_mfma_f32_16x16x32_f16(
                    a_hi[ni], b_lo, acc[ni][mj], 0, 0, 0);
                acc[ni][mj] = __builtin_amdgcn_mfma_f32_16x16x32_f16(
                    a_lo[ni], b_hi, acc[ni][mj], 0, 0, 0);
            }
        }
    }

    #pragma unroll
    for (int ni = 0; ni < 2; ++ni)
        #pragma unroll
        for (int mj = 0; mj < 8; ++mj) {
            if (mode == 2) {
                const int s  = n0 + wave * 32 + ni * 16 + quad * 4;
                const int b  = s >> 11;
                const int sr = s & (S_ - 1);
                const int m  = m0 + mj * 16 + row16;
                const int h  = m >> 6;
                const int dk = m & 63;
                half4 h4;
                #pragma unroll
                for (int r = 0; r < 4; ++r) h4[r] = (_Float16)acc[ni][mj][r];
                *(half4*)((_Float16*)out0 +
                          (((size_t)b * H_ + h) * DK_ + dk) * S_ + sr) = h4;
            } else {
                #pragma unroll
                for (int rg = 0; rg < 4; ++rg) {
                    const int n = n0 + wave * 32 + ni * 16 + quad * 4 + rg;
                    const int m = m0 + mj * 16 + row16;
                    const float v = acc[ni][mj][rg];
                    if (mode == 0) {
                        ((float*)out0)[(size_t)n * D_ + m] = v;
                    } else {
                        const int b  = n >> 11;
                        const int s  = n & (S_ - 1);
                        const int h  = m >> 6;
                        const int dk = m & 63;
                        union { _Float16 h16; uint16_t u; } hi, lo;
                        hi.h16 = (_Float16)v;
                        lo.h16 = (_Float16)(v - (float)hi.h16);
                        uint32_t u = ((uint32_t)lo.u << 16) | (uint32_t)hi.u;
                        ((uint32_t*)out0)[(((size_t)b * H_ + h) * S_ + s) * DK_ + dk] = u;
                    }
                }
            }
        }
}

// ---------------------------------------------------------------------------
// MFMA flash attention v3 -- UNCHANGED from round 3 (proven: VGPR 80, no
// scratch spill, 238 us). Q/K arrive packed u32 {lo16,hi16}; V arrives f16
// [B,H,DK,S]; output written as split hi/lo f16 A planes for the Wo GEMM.
// ---------------------------------------------------------------------------
__global__ __launch_bounds__(256)
void attn_mfma(const uint32_t* __restrict__ Qhl, const uint32_t* __restrict__ Khl,
               const _Float16* __restrict__ Vth,
               _Float16* __restrict__ Ahi, _Float16* __restrict__ Alo) {
    __shared__ __align__(16) _Float16 KhiC[64][64];
    __shared__ __align__(16) _Float16 KloC[64][64];
    __shared__ __align__(16) _Float16 VC[64][64];
    __shared__ __align__(16) _Float16 PCT[4][16][72];   // [wave][q][k]

    const int bh = blockIdx.y;
    const int qt = (int)(gridDim.x - 1) - (int)blockIdx.x;  // heavy tiles first
    const int q0 = qt * 64;
    const int tid  = threadIdx.x;
    const int wave = tid >> 6;
    const int lane = tid & 63;
    const int c    = lane & 15;
    const int quad = lane >> 4;

    const uint32_t* Kb = Khl + (size_t)bh * S_ * DK_;
    const _Float16* Vb = Vth + (size_t)bh * DK_ * S_;

    // Q fragment (B-operand): lane holds q-row (q0+16w+c), k = ks*32+quad*8+j
    half8 qhi[2], qlo[2];
    {
        const uint32_t* Qrow = Qhl + ((size_t)bh * S_ + q0 + wave * 16 + c) * DK_;
        #pragma unroll
        for (int ks = 0; ks < 2; ++ks) {
            uint32_t u[8];
            *(uint4*)&u[0] = *(const uint4*)(Qrow + ks * 32 + quad * 8);
            *(uint4*)&u[4] = *(const uint4*)(Qrow + ks * 32 + quad * 8 + 4);
            union { half8 v; uint16_t s[8]; } hi, lo;
            #pragma unroll
            for (int j = 0; j < 8; ++j) {
                hi.s[j] = (uint16_t)(u[j] & 0xffffu);
                lo.s[j] = (uint16_t)(u[j] >> 16);
            }
            qhi[ks] = hi.v; qlo[ks] = lo.v;
        }
    }

    floatx4 acc_o[4];   // O^T: acc_o[dt][r] = O[q=lane-col][dk=dt*16+quad*4+r]
    const floatx4 zero4 = {0.f, 0.f, 0.f, 0.f};
    #pragma unroll
    for (int dt = 0; dt < 4; ++dt) acc_o[dt] = zero4;
    float mrun = -INFINITY, lrun = 0.f;

    // staging: thread -> (row srow, 16-elem segment); chunk = 8 halves = 16 B
    const int srow = tid >> 2;
    const int soff = (tid & 3) * 16;
    const int ch0  = (tid & 3) * 2;

    uint4 ku[4];
    uint4 vv[2];
    auto load_tile = [&](int kt) {
        const uint4* ksrc = (const uint4*)(Kb + (size_t)(kt * 64 + srow) * DK_ + soff);
        ku[0] = ksrc[0]; ku[1] = ksrc[1]; ku[2] = ksrc[2]; ku[3] = ksrc[3];
        const uint4* vsrc = (const uint4*)(Vb + (size_t)srow * S_ + kt * 64 + soff);
        vv[0] = vsrc[0]; vv[1] = vsrc[1];
    };
    auto write_tile = [&]() {
        #pragma unroll
        for (int hf = 0; hf < 2; ++hf) {
            const int swz = ((ch0 + hf) ^ (srow & 7)) * 8;
            uint32_t uu[8];
            *(uint4*)&uu[0] = ku[2 * hf];
            *(uint4*)&uu[4] = ku[2 * hf + 1];
            union { half8 v; uint16_t s[8]; } hi, lo;
            #pragma unroll
            for (int j = 0; j < 8; ++j) {
                hi.s[j] = (uint16_t)(uu[j] & 0xffffu);
                lo.s[j] = (uint16_t)(uu[j] >> 16);
            }
            *(half8*)&KhiC[srow][swz] = hi.v;
            *(half8*)&KloC[srow][swz] = lo.v;
            *(uint4*)&VC[srow][swz]   = vv[hf];
        }
    };

    const int qmy = q0 + wave * 16 + c;   // this lane's q-row
    const floatx4 neg4 = {-INFINITY, -INFINITY, -INFINITY, -INFINITY};

    load_tile(0);
    write_tile();

    for (int kt = 0; kt <= qt; ++kt) {
        const int k0 = kt * 64;
        const bool diag = (kt == qt);
        __syncthreads();                     // tile kt visible in LDS
        if (kt < qt) load_tile(kt + 1);      // prefetch overlaps compute

        // S^T tiles: sc[t][r] = S[q=qmy][k = k0 + t*16 + quad*4 + r] (unscaled)
        floatx4 sc[4];
        #pragma unroll
        for (int t = 0; t < 4; ++t) {
            if (diag && t > wave) { sc[t] = neg4; continue; }
            floatx4 s4 = zero4;
            const int krow = t * 16 + c;
            #pragma unroll
            for (int ks = 0; ks < 2; ++ks) {
                const int swz = ((ks * 4 + quad) ^ (krow & 7)) * 8;
                half8 kb = *(const half8*)&KhiC[krow][swz];
                half8 kl = *(const half8*)&KloC[krow][swz];
                s4 = __builtin_amdgcn_mfma_f32_16x16x32_f16(kb, qhi[ks], s4, 0, 0, 0);
                s4 = __builtin_amdgcn_mfma_f32_16x16x32_f16(kl, qhi[ks], s4, 0, 0, 0);
                s4 = __builtin_amdgcn_mfma_f32_16x16x32_f16(kb, qlo[ks], s4, 0, 0, 0);
            }
            #pragma unroll
            for (int r = 0; r < 4; ++r) s4[r] *= 0.125f;
            if (diag && t == wave) {
                #pragma unroll
                for (int r = 0; r < 4; ++r) {
                    const int k = k0 + t * 16 + quad * 4 + r;
                    if (k > qmy) s4[r] = -INFINITY;
                }
            }
            sc[t] = s4;
        }

        // online softmax: in-lane max over 16, 2 cross-quad shuffles
        float mx = -INFINITY;
        #pragma unroll
        for (int t = 0; t < 4; ++t)
            #pragma unroll
            for (int r = 0; r < 4; ++r) mx = fmaxf(mx, sc[t][r]);
        mx = fmaxf(mx, __shfl_xor(mx, 16));
        mx = fmaxf(mx, __shfl_xor(mx, 32));
        const float mnew  = fmaxf(mrun, mx);
        const float alpha = __expf(mrun - mnew);
        float ls = 0.f;
        #pragma unroll
        for (int t = 0; t < 4; ++t) {
            half4 p4;
            #pragma unroll
            for (int r = 0; r < 4; ++r) {
                const float p = __expf(sc[t][r] - mnew);
                ls += p;
                p4[r] = (_Float16)p;
            }
            // P^T store: PCT[wave][q=c][k-local = t*16+quad*4 .. +3]
            *(half4*)&PCT[wave][c][t * 16 + quad * 4] = p4;
        }
        lrun = alpha * lrun + ls;
        mrun = mnew;
        #pragma unroll
        for (int dt = 0; dt < 4; ++dt)
            #pragma unroll
            for (int r = 0; r < 4; ++r) acc_o[dt][r] *= alpha;

        // O^T += V^T P^T  (A-frag = V^T rows, B-frag = P rows; same-wave RAW)
        #pragma unroll
        for (int kc = 0; kc < 2; ++kc) {
            if (diag && kc == 1 && wave < 2) continue;   // P chunk all-zero
            half8 pb = *(const half8*)&PCT[wave][c][kc * 32 + quad * 8];
            #pragma unroll
            for (int dt = 0; dt < 4; ++dt) {
                const int vrow = dt * 16 + c;
                const int swz = ((kc * 4 + quad) ^ (vrow & 7)) * 8;
                half8 va = *(const half8*)&VC[vrow][swz];
                acc_o[dt] = __builtin_amdgcn_mfma_f32_16x16x32_f16(va, pb, acc_o[dt], 0, 0, 0);
            }
        }

        __syncthreads();                     // all reads of tile kt done
        if (kt < qt) write_tile();
    }

    // final l across quads, normalize, write split hi/lo A planes [B,S,D]
    float l = lrun;
    l += __shfl_xor(l, 16);
    l += __shfl_xor(l, 32);
    const float inv = 1.f / l;
    const int b = bh >> 4, h = bh & 15;
    _Float16* dh = Ahi + ((size_t)b * S_ + qmy) * D_ + h * DK_;
    _Float16* dl = Alo + ((size_t)b * S_ + qmy) * D_ + h * DK_;
    #pragma unroll
    for (int dt = 0; dt < 4; ++dt) {
        half4 hh, ll;
        #pragma unroll
        for (int r = 0; r < 4; ++r) {
            const float o = acc_o[dt][r] * inv;
            hh[r] = (_Float16)o;
            ll[r] = (_Float16)(o - (float)hh[r]);
        }
        *(half4*)(dh + dt * 16 + quad * 4) = hh;
        *(half4*)(dl + dt * 16 + quad * 4) = ll;
    }
}

// ---------------------------------------------------------------------------
extern "C" void kernel_launch(void* const* d_in, const int* in_sizes, int n_in,
                              void* d_out, int out_size, void* d_ws, size_t ws_size,
                              hipStream_t stream) {
    const float* q  = (const float*)d_in[0];
    const float* k  = (const float*)d_in[1];
    const float* v  = (const float*)d_in[2];
    const float* Wq = (const float*)d_in[3];
    const float* Wk = (const float*)d_in[4];
    const float* Wv = (const float*)d_in[5];
    const float* Wo = (const float*)d_in[6];
    float* out = (float*)d_out;

    const size_t SZ  = (size_t)B_ * S_ * D_;   // 8,388,608 elements
    const size_t WSZ = (size_t)D_ * D_;        // 1,048,576 elements

    // workspace layout (in halves): 7*SZ + 2*WSZ = ~122 MB
    _Float16* ws  = (_Float16*)d_ws;
    _Float16* xhi = ws;                        // [NR, D]  (reused as Ahi)
    _Float16* xlo = xhi + SZ;                  // [NR, D]  (reused as Alo)
    _Float16* whi = xlo + SZ;                  // [D, D]   (shared by 4 weights)
    _Float16* wlo = whi + WSZ;
    uint32_t* Qhl = (uint32_t*)(wlo + WSZ);    // packed u32 [B,H,S,DK] (2*SZ halves)
    uint32_t* Khl = (uint32_t*)(wlo + WSZ + 2 * SZ);  // packed u32 (2*SZ halves)
    _Float16* Vth = wlo + WSZ + 4 * SZ;        // f16 [B,H,DK,S] (SZ halves)
    _Float16* Ahi = xhi;
    _Float16* Alo = xlo;

    const int nx8 = (int)(SZ / 8);   // 1,048,576 -> 4096 blocks
    const int nw8 = (int)(WSZ / 8);  //   131,072 ->  512 blocks
    dim3 gb(NR_ / GBN, D_ / GBM);    // 64 x 8
    dim3 ga(S_ / 64, B_ * H_);       // 32 x 64

    split_f32<<<nw8 / 256, 256, 0, stream>>>(Wq, whi, wlo, nw8);
    split_f32<<<nx8 / 256, 256, 0, stream>>>(q, xhi, xlo, nx8);
    gemm_xwt_mfma<<<gb, 256, 0, stream>>>(xhi, xlo, whi, wlo, Qhl, 1);

    split_f32<<<nw8 / 256, 256, 0, stream>>>(Wk, whi, wlo, nw8);
    split_f32<<<nx8 / 256, 256, 0, stream>>>(k, xhi, xlo, nx8);
    gemm_xwt_mfma<<<gb, 256, 0, stream>>>(xhi, xlo, whi, wlo, Khl, 1);

    split_f32<<<nw8 / 256, 256, 0, stream>>>(Wv, whi, wlo, nw8);
    split_f32<<<nx8 / 256, 256, 0, stream>>>(v, xhi, xlo, nx8);
    gemm_xwt_mfma<<<gb, 256, 0, stream>>>(xhi, xlo, whi, wlo, Vth, 2);

    attn_mfma<<<ga, 256, 0, stream>>>(Qhl, Khl, Vth, Ahi, Alo);

    split_f32<<<nw8 / 256, 256, 0, stream>>>(Wo, whi, wlo, nw8);
    gemm_xwt_mfma<<<gb, 256, 0, stream>>>(Ahi, Alo, whi, wlo, out, 0);
}

// Round 5
// 616.178 us; speedup vs baseline: 1.4548x; 1.0112x over previous
//
#include <hip/hip_runtime.h>
#include <math.h>
#include <stdint.h>

#define B_  4
#define S_  2048
#define D_  1024
#define H_  16
#define DK_ 64
#define NR_ (B_ * S_)   // 8192 rows

typedef _Float16 half8  __attribute__((ext_vector_type(8)));
typedef _Float16 half4  __attribute__((ext_vector_type(4)));
typedef float    floatx4 __attribute__((ext_vector_type(4)));

// ---------------------------------------------------------------------------
// One-time fp32 -> split-f16 (hi/lo planes) for GEMM X inputs. Memory-bound.
// ---------------------------------------------------------------------------
__global__ __launch_bounds__(256)
void split_f32(const float* __restrict__ src, _Float16* __restrict__ hi,
               _Float16* __restrict__ lo, int n8) {
    const int i = blockIdx.x * 256 + threadIdx.x;
    if (i >= n8) return;
    const float4* s4 = (const float4*)src;
    float4 a = s4[2 * i];
    float4 b = s4[2 * i + 1];
    float f[8] = {a.x, a.y, a.z, a.w, b.x, b.y, b.z, b.w};
    union { half8 v; _Float16 h[8]; } H, L;
    #pragma unroll
    for (int j = 0; j < 8; ++j) {
        _Float16 h = (_Float16)f[j];
        H.h[j] = h;
        L.h[j] = (_Float16)(f[j] - (float)h);
    }
    *(half8*)(hi + (size_t)i * 8) = H.v;
    *(half8*)(lo + (size_t)i * 8) = L.v;
}

// Batched weight split: all 4 weights in one launch (blockIdx.y selects).
// Planes at wbase + y*2*WSZ (hi), +WSZ (lo).
__global__ __launch_bounds__(256)
void split_w4(const float* __restrict__ w0, const float* __restrict__ w1,
              const float* __restrict__ w2, const float* __restrict__ w3,
              _Float16* __restrict__ wbase, int n8) {
    const int i = blockIdx.x * 256 + threadIdx.x;
    if (i >= n8) return;
    const float* src = (blockIdx.y == 0) ? w0 : (blockIdx.y == 1) ? w1 :
                       (blockIdx.y == 2) ? w2 : w3;
    _Float16* hi = wbase + (size_t)blockIdx.y * 2 * ((size_t)D_ * D_);
    _Float16* lo = hi + (size_t)D_ * D_;
    const float4* s4 = (const float4*)src;
    float4 a = s4[2 * i];
    float4 b = s4[2 * i + 1];
    float f[8] = {a.x, a.y, a.z, a.w, b.x, b.y, b.z, b.w};
    union { half8 v; _Float16 h[8]; } H, L;
    #pragma unroll
    for (int j = 0; j < 8; ++j) {
        _Float16 h = (_Float16)f[j];
        H.h[j] = h;
        L.h[j] = (_Float16)(f[j] - (float)h);
    }
    *(half8*)(hi + (size_t)i * 8) = H.v;
    *(half8*)(lo + (size_t)i * 8) = L.v;
}

// ---------------------------------------------------------------------------
// GEMM: out = X @ W^T via split-f16 MFMA (fp32-accurate), tile 128x128.
// Round-5: A-fragments load DIRECTLY global->register (the 16x16x32 A-frag
// layout == row-major global layout), prefetched one K-step ahead; only W
// is staged in LDS. Theory: round-4 was LDS-instruction-throughput bound
// (28 LDS ops/thread/K-step vs MFMA 233 cyc/SIMD); this cuts LDS ops to 20
// and halves the barrier-protected write phase. X panel is L2-resident
// (8 m-blocks reuse it), so direct loads hit L2. Numerics bit-identical.
// Epilogue modes:
//   0: fp32 [N x M] row-major                        (Wo projection -> d_out)
//   1: packed u32 {lo16,hi16} f16 split, [B,H,S,DK]  (Q,K projections)
//   2: f16 transposed head-split [B,H,DK,S]          (V projection)
// ---------------------------------------------------------------------------
#define GBN 128
#define GBM 128
#define GBK 32
#define LDH 40

__global__ __launch_bounds__(256, 3)
void gemm_xwt_mfma(const _Float16* __restrict__ Xh, const _Float16* __restrict__ Xl,
                   const _Float16* __restrict__ Wh, const _Float16* __restrict__ Wl,
                   void* __restrict__ out0, int mode) {
    __shared__ __align__(16) _Float16 Whi[GBM][LDH];
    __shared__ __align__(16) _Float16 Wlo[GBM][LDH];
    const int K = D_;

    const int tid  = threadIdx.x;
    const int wave = tid >> 6;
    const int lane = tid & 63;
    const int row16 = lane & 15;
    const int quad  = lane >> 4;
    const int n0 = blockIdx.x * GBN;
    const int m0 = blockIdx.y * GBM;

    // W staging map: 128 rows x 32 halves, 2 threads/row (16 halves each)
    const int wrow = tid >> 1;
    const int wc   = (tid & 1) << 4;

    // A-fragment global base: lane (row16,quad) of wave covers
    // X[n0 + wave*32 + ni*16 + row16][k0 + quad*8 .. +8]  (row-major match)
    const _Float16* aHb = Xh + (size_t)(n0 + wave * 32 + row16) * K + quad * 8;
    const _Float16* aLb = Xl + (size_t)(n0 + wave * 32 + row16) * K + quad * 8;

    floatx4 acc[2][8];
    const floatx4 zero4 = {0.f, 0.f, 0.f, 0.f};
    #pragma unroll
    for (int i = 0; i < 2; ++i)
        #pragma unroll
        for (int j = 0; j < 8; ++j) acc[i][j] = zero4;

    half8 pa_h0, pa_h1, pa_l0, pa_l1;
    uint4 wh0, wh1, wl0, wl1;
    auto load_regs = [&](int k0) {
        pa_h0 = *(const half8*)(aHb + k0);
        pa_h1 = *(const half8*)(aHb + (size_t)16 * K + k0);
        pa_l0 = *(const half8*)(aLb + k0);
        pa_l1 = *(const half8*)(aLb + (size_t)16 * K + k0);
        const _Float16* pwh = Wh + (size_t)(m0 + wrow) * K + k0 + wc;
        const _Float16* pwl = Wl + (size_t)(m0 + wrow) * K + k0 + wc;
        wh0 = *(const uint4*)pwh;
        wh1 = *(const uint4*)(pwh + 8);
        wl0 = *(const uint4*)pwl;
        wl1 = *(const uint4*)(pwl + 8);
    };

    load_regs(0);
    for (int k0 = 0; k0 < K; k0 += GBK) {
        // capture current A-frags before prefetch overwrites them
        half8 a_hi[2] = {pa_h0, pa_h1};
        half8 a_lo[2] = {pa_l0, pa_l1};
        __syncthreads();                 // prev iteration's b-reads done
        *(uint4*)&Whi[wrow][wc]     = wh0;
        *(uint4*)&Whi[wrow][wc + 8] = wh1;
        *(uint4*)&Wlo[wrow][wc]     = wl0;
        *(uint4*)&Wlo[wrow][wc + 8] = wl1;
        __syncthreads();                 // W tile visible
        if (k0 + GBK < K) load_regs(k0 + GBK);   // overlaps MFMAs below

        #pragma unroll
        for (int mj = 0; mj < 8; ++mj) {
            const int r = mj * 16 + row16;
            half8 b_hi = *(const half8*)&Whi[r][quad * 8];
            half8 b_lo = *(const half8*)&Wlo[r][quad * 8];
            #pragma unroll
            for (int ni = 0; ni < 2; ++ni) {
                acc[ni][mj] = __builtin_amdgcn_mfma_f32_16x16x32_f16(
                    a_hi[ni], b_hi, acc[ni][mj], 0, 0, 0);
                acc[ni][mj] = __builtin_amdgcn_mfma_f32_16x16x32_f16(
                    a_hi[ni], b_lo, acc[ni][mj], 0, 0, 0);
                acc[ni][mj] = __builtin_amdgcn_mfma_f32_16x16x32_f16(
                    a_lo[ni], b_hi, acc[ni][mj], 0, 0, 0);
            }
        }
    }

    #pragma unroll
    for (int ni = 0; ni < 2; ++ni)
        #pragma unroll
        for (int mj = 0; mj < 8; ++mj) {
            if (mode == 2) {
                const int s  = n0 + wave * 32 + ni * 16 + quad * 4;
                const int b  = s >> 11;
                const int sr = s & (S_ - 1);
                const int m  = m0 + mj * 16 + row16;
                const int h  = m >> 6;
                const int dk = m & 63;
                half4 h4;
                #pragma unroll
                for (int r = 0; r < 4; ++r) h4[r] = (_Float16)acc[ni][mj][r];
                *(half4*)((_Float16*)out0 +
                          (((size_t)b * H_ + h) * DK_ + dk) * S_ + sr) = h4;
            } else {
                #pragma unroll
                for (int rg = 0; rg < 4; ++rg) {
                    const int n = n0 + wave * 32 + ni * 16 + quad * 4 + rg;
                    const int m = m0 + mj * 16 + row16;
                    const float v = acc[ni][mj][rg];
                    if (mode == 0) {
                        ((float*)out0)[(size_t)n * D_ + m] = v;
                    } else {
                        const int b  = n >> 11;
                        const int s  = n & (S_ - 1);
                        const int h  = m >> 6;
                        const int dk = m & 63;
                        union { _Float16 h16; uint16_t u; } hi, lo;
                        hi.h16 = (_Float16)v;
                        lo.h16 = (_Float16)(v - (float)hi.h16);
                        uint32_t u = ((uint32_t)lo.u << 16) | (uint32_t)hi.u;
                        ((uint32_t*)out0)[(((size_t)b * H_ + h) * S_ + s) * DK_ + dk] = u;
                    }
                }
            }
        }
}

// ---------------------------------------------------------------------------
// MFMA flash attention v3 -- UNCHANGED from round 3/4 (proven: VGPR 80, no
// scratch spill, ~240 us). Q/K arrive packed u32 {lo16,hi16}; V arrives f16
// [B,H,DK,S]; output written as split hi/lo f16 A planes for the Wo GEMM.
// ---------------------------------------------------------------------------
__global__ __launch_bounds__(256)
void attn_mfma(const uint32_t* __restrict__ Qhl, const uint32_t* __restrict__ Khl,
               const _Float16* __restrict__ Vth,
               _Float16* __restrict__ Ahi, _Float16* __restrict__ Alo) {
    __shared__ __align__(16) _Float16 KhiC[64][64];
    __shared__ __align__(16) _Float16 KloC[64][64];
    __shared__ __align__(16) _Float16 VC[64][64];
    __shared__ __align__(16) _Float16 PCT[4][16][72];   // [wave][q][k]

    const int bh = blockIdx.y;
    const int qt = (int)(gridDim.x - 1) - (int)blockIdx.x;  // heavy tiles first
    const int q0 = qt * 64;
    const int tid  = threadIdx.x;
    const int wave = tid >> 6;
    const int lane = tid & 63;
    const int c    = lane & 15;
    const int quad = lane >> 4;

    const uint32_t* Kb = Khl + (size_t)bh * S_ * DK_;
    const _Float16* Vb = Vth + (size_t)bh * DK_ * S_;

    // Q fragment (B-operand): lane holds q-row (q0+16w+c), k = ks*32+quad*8+j
    half8 qhi[2], qlo[2];
    {
        const uint32_t* Qrow = Qhl + ((size_t)bh * S_ + q0 + wave * 16 + c) * DK_;
        #pragma unroll
        for (int ks = 0; ks < 2; ++ks) {
            uint32_t u[8];
            *(uint4*)&u[0] = *(const uint4*)(Qrow + ks * 32 + quad * 8);
            *(uint4*)&u[4] = *(const uint4*)(Qrow + ks * 32 + quad * 8 + 4);
            union { half8 v; uint16_t s[8]; } hi, lo;
            #pragma unroll
            for (int j = 0; j < 8; ++j) {
                hi.s[j] = (uint16_t)(u[j] & 0xffffu);
                lo.s[j] = (uint16_t)(u[j] >> 16);
            }
            qhi[ks] = hi.v; qlo[ks] = lo.v;
        }
    }

    floatx4 acc_o[4];   // O^T: acc_o[dt][r] = O[q=lane-col][dk=dt*16+quad*4+r]
    const floatx4 zero4 = {0.f, 0.f, 0.f, 0.f};
    #pragma unroll
    for (int dt = 0; dt < 4; ++dt) acc_o[dt] = zero4;
    float mrun = -INFINITY, lrun = 0.f;

    // staging: thread -> (row srow, 16-elem segment); chunk = 8 halves = 16 B
    const int srow = tid >> 2;
    const int soff = (tid & 3) * 16;
    const int ch0  = (tid & 3) * 2;

    uint4 ku[4];
    uint4 vv[2];
    auto load_tile = [&](int kt) {
        const uint4* ksrc = (const uint4*)(Kb + (size_t)(kt * 64 + srow) * DK_ + soff);
        ku[0] = ksrc[0]; ku[1] = ksrc[1]; ku[2] = ksrc[2]; ku[3] = ksrc[3];
        const uint4* vsrc = (const uint4*)(Vb + (size_t)srow * S_ + kt * 64 + soff);
        vv[0] = vsrc[0]; vv[1] = vsrc[1];
    };
    auto write_tile = [&]() {
        #pragma unroll
        for (int hf = 0; hf < 2; ++hf) {
            const int swz = ((ch0 + hf) ^ (srow & 7)) * 8;
            uint32_t uu[8];
            *(uint4*)&uu[0] = ku[2 * hf];
            *(uint4*)&uu[4] = ku[2 * hf + 1];
            union { half8 v; uint16_t s[8]; } hi, lo;
            #pragma unroll
            for (int j = 0; j < 8; ++j) {
                hi.s[j] = (uint16_t)(uu[j] & 0xffffu);
                lo.s[j] = (uint16_t)(uu[j] >> 16);
            }
            *(half8*)&KhiC[srow][swz] = hi.v;
            *(half8*)&KloC[srow][swz] = lo.v;
            *(uint4*)&VC[srow][swz]   = vv[hf];
        }
    };

    const int qmy = q0 + wave * 16 + c;   // this lane's q-row
    const floatx4 neg4 = {-INFINITY, -INFINITY, -INFINITY, -INFINITY};

    load_tile(0);
    write_tile();

    for (int kt = 0; kt <= qt; ++kt) {
        const int k0 = kt * 64;
        const bool diag = (kt == qt);
        __syncthreads();                     // tile kt visible in LDS
        if (kt < qt) load_tile(kt + 1);      // prefetch overlaps compute

        // S^T tiles: sc[t][r] = S[q=qmy][k = k0 + t*16 + quad*4 + r] (unscaled)
        floatx4 sc[4];
        #pragma unroll
        for (int t = 0; t < 4; ++t) {
            if (diag && t > wave) { sc[t] = neg4; continue; }
            floatx4 s4 = zero4;
            const int krow = t * 16 + c;
            #pragma unroll
            for (int ks = 0; ks < 2; ++ks) {
                const int swz = ((ks * 4 + quad) ^ (krow & 7)) * 8;
                half8 kb = *(const half8*)&KhiC[krow][swz];
                half8 kl = *(const half8*)&KloC[krow][swz];
                s4 = __builtin_amdgcn_mfma_f32_16x16x32_f16(kb, qhi[ks], s4, 0, 0, 0);
                s4 = __builtin_amdgcn_mfma_f32_16x16x32_f16(kl, qhi[ks], s4, 0, 0, 0);
                s4 = __builtin_amdgcn_mfma_f32_16x16x32_f16(kb, qlo[ks], s4, 0, 0, 0);
            }
            #pragma unroll
            for (int r = 0; r < 4; ++r) s4[r] *= 0.125f;
            if (diag && t == wave) {
                #pragma unroll
                for (int r = 0; r < 4; ++r) {
                    const int k = k0 + t * 16 + quad * 4 + r;
                    if (k > qmy) s4[r] = -INFINITY;
                }
            }
            sc[t] = s4;
        }

        // online softmax: in-lane max over 16, 2 cross-quad shuffles
        float mx = -INFINITY;
        #pragma unroll
        for (int t = 0; t < 4; ++t)
            #pragma unroll
            for (int r = 0; r < 4; ++r) mx = fmaxf(mx, sc[t][r]);
        mx = fmaxf(mx, __shfl_xor(mx, 16));
        mx = fmaxf(mx, __shfl_xor(mx, 32));
        const float mnew  = fmaxf(mrun, mx);
        const float alpha = __expf(mrun - mnew);
        float ls = 0.f;
        #pragma unroll
        for (int t = 0; t < 4; ++t) {
            half4 p4;
            #pragma unroll
            for (int r = 0; r < 4; ++r) {
                const float p = __expf(sc[t][r] - mnew);
                ls += p;
                p4[r] = (_Float16)p;
            }
            // P^T store: PCT[wave][q=c][k-local = t*16+quad*4 .. +3]
            *(half4*)&PCT[wave][c][t * 16 + quad * 4] = p4;
        }
        lrun = alpha * lrun + ls;
        mrun = mnew;
        #pragma unroll
        for (int dt = 0; dt < 4; ++dt)
            #pragma unroll
            for (int r = 0; r < 4; ++r) acc_o[dt][r] *= alpha;

        // O^T += V^T P^T  (A-frag = V^T rows, B-frag = P rows; same-wave RAW)
        #pragma unroll
        for (int kc = 0; kc < 2; ++kc) {
            if (diag && kc == 1 && wave < 2) continue;   // P chunk all-zero
            half8 pb = *(const half8*)&PCT[wave][c][kc * 32 + quad * 8];
            #pragma unroll
            for (int dt = 0; dt < 4; ++dt) {
                const int vrow = dt * 16 + c;
                const int swz = ((kc * 4 + quad) ^ (vrow & 7)) * 8;
                half8 va = *(const half8*)&VC[vrow][swz];
                acc_o[dt] = __builtin_amdgcn_mfma_f32_16x16x32_f16(va, pb, acc_o[dt], 0, 0, 0);
            }
        }

        __syncthreads();                     // all reads of tile kt done
        if (kt < qt) write_tile();
    }

    // final l across quads, normalize, write split hi/lo A planes [B,S,D]
    float l = lrun;
    l += __shfl_xor(l, 16);
    l += __shfl_xor(l, 32);
    const float inv = 1.f / l;
    const int b = bh >> 4, h = bh & 15;
    _Float16* dh = Ahi + ((size_t)b * S_ + qmy) * D_ + h * DK_;
    _Float16* dl = Alo + ((size_t)b * S_ + qmy) * D_ + h * DK_;
    #pragma unroll
    for (int dt = 0; dt < 4; ++dt) {
        half4 hh, ll;
        #pragma unroll
        for (int r = 0; r < 4; ++r) {
            const float o = acc_o[dt][r] * inv;
            hh[r] = (_Float16)o;
            ll[r] = (_Float16)(o - (float)hh[r]);
        }
        *(half4*)(dh + dt * 16 + quad * 4) = hh;
        *(half4*)(dl + dt * 16 + quad * 4) = ll;
    }
}

// ---------------------------------------------------------------------------
extern "C" void kernel_launch(void* const* d_in, const int* in_sizes, int n_in,
                              void* d_out, int out_size, void* d_ws, size_t ws_size,
                              hipStream_t stream) {
    const float* q  = (const float*)d_in[0];
    const float* k  = (const float*)d_in[1];
    const float* v  = (const float*)d_in[2];
    const float* Wq = (const float*)d_in[3];
    const float* Wk = (const float*)d_in[4];
    const float* Wv = (const float*)d_in[5];
    const float* Wo = (const float*)d_in[6];
    float* out = (float*)d_out;

    const size_t SZ  = (size_t)B_ * S_ * D_;   // 8,388,608 elements
    const size_t WSZ = (size_t)D_ * D_;        // 1,048,576 elements

    // workspace layout (in halves): 7*SZ + 8*WSZ = 134.2 MB (== round-0 footprint)
    _Float16* ws    = (_Float16*)d_ws;
    _Float16* xhi   = ws;                       // [NR, D]  (reused as Ahi)
    _Float16* xlo   = xhi + SZ;                 // [NR, D]  (reused as Alo)
    _Float16* wbase = xlo + SZ;                 // 4 x {hi[D,D], lo[D,D]}
    uint32_t* Qhl = (uint32_t*)(wbase + 8 * WSZ);         // packed u32 (2*SZ halves)
    uint32_t* Khl = (uint32_t*)(wbase + 8 * WSZ + 2 * SZ);// packed u32 (2*SZ halves)
    _Float16* Vth = wbase + 8 * WSZ + 4 * SZ;   // f16 [B,H,DK,S] (SZ halves)
    _Float16* Ahi = xhi;
    _Float16* Alo = xlo;

    _Float16* wq_hi = wbase + 0 * 2 * WSZ, *wq_lo = wq_hi + WSZ;
    _Float16* wk_hi = wbase + 1 * 2 * WSZ, *wk_lo = wk_hi + WSZ;
    _Float16* wv_hi = wbase + 2 * 2 * WSZ, *wv_lo = wv_hi + WSZ;
    _Float16* wo_hi = wbase + 3 * 2 * WSZ, *wo_lo = wo_hi + WSZ;

    const int nx8 = (int)(SZ / 8);   // 1,048,576 -> 4096 blocks
    const int nw8 = (int)(WSZ / 8);  //   131,072 ->  512 blocks
    dim3 gb(NR_ / GBN, D_ / GBM);    // 64 x 8
    dim3 ga(S_ / 64, B_ * H_);       // 32 x 64
    dim3 gw(nw8 / 256, 4);           // 512 x 4

    split_w4<<<gw, 256, 0, stream>>>(Wq, Wk, Wv, Wo, wbase, nw8);

    split_f32<<<nx8 / 256, 256, 0, stream>>>(q, xhi, xlo, nx8);
    gemm_xwt_mfma<<<gb, 256, 0, stream>>>(xhi, xlo, wq_hi, wq_lo, Qhl, 1);

    split_f32<<<nx8 / 256, 256, 0, stream>>>(k, xhi, xlo, nx8);
    gemm_xwt_mfma<<<gb, 256, 0, stream>>>(xhi, xlo, wk_hi, wk_lo, Khl, 1);

    split_f32<<<nx8 / 256, 256, 0, stream>>>(v, xhi, xlo, nx8);
    gemm_xwt_mfma<<<gb, 256, 0, stream>>>(xhi, xlo, wv_hi, wv_lo, Vth, 2);

    attn_mfma<<<ga, 256, 0, stream>>>(Qhl, Khl, Vth, Ahi, Alo);

    gemm_xwt_mfma<<<gb, 256, 0, stream>>>(Ahi, Alo, wo_hi, wo_lo, out, 0);
}